// Round 9
// baseline (259.276 us; speedup 1.0000x reference)
//
#include <hip/hip_runtime.h>
#include <math.h>

#define H1 224
#define W1 224
#define H2 112
#define W2 112
#define HP 56
#define WP 56

#define NS 32
#define SLOT_STRIDE 64

// ---------------- complex helpers (quantum circuit) ----------------
struct C2 { float re, im; };
__device__ __forceinline__ C2 cmul(C2 a, C2 b) {
    return C2{fmaf(a.re, b.re, -a.im * b.im), fmaf(a.re, b.im, a.im * b.re)};
}
__device__ __forceinline__ C2 cadd(C2 a, C2 b) { return C2{a.re + b.re, a.im + b.im}; }

template <int S>
__device__ __forceinline__ void ap1s(C2* st, C2 u00, C2 u01, C2 u10, C2 u11) {
#pragma unroll
    for (int i = 0; i < 16; i++) {
        if (i & S) continue;
        C2 a0 = st[i], a1 = st[i + S];
        st[i]     = cadd(cmul(u00, a0), cmul(u01, a1));
        st[i + S] = cadd(cmul(u10, a0), cmul(u11, a1));
    }
}
template <int SC, int STT>
__device__ __forceinline__ void cnot_s(C2* st) {
#pragma unroll
    for (int i = 0; i < 16; i++)
        if ((i & SC) && !(i & STT)) { C2 t = st[i]; st[i] = st[i + STT]; st[i + STT] = t; }
}
struct M2 { C2 m[2][2]; };
__device__ __forceinline__ M2 mmul(const M2& A, const M2& B) {
    M2 R;
#pragma unroll
    for (int i = 0; i < 2; i++)
#pragma unroll
        for (int j = 0; j < 2; j++)
            R.m[i][j] = cadd(cmul(A.m[i][0], B.m[0][j]), cmul(A.m[i][1], B.m[1][j]));
    return R;
}
// combined U = Rx(p2) * Rz(p1) * Ry(p0)
__device__ __forceinline__ M2 combined_u(const float* __restrict__ p) {
    float c0 = cosf(0.5f * p[0]), s0 = sinf(0.5f * p[0]);
    float c1 = cosf(0.5f * p[1]), s1 = sinf(0.5f * p[1]);
    float c2 = cosf(0.5f * p[2]), s2 = sinf(0.5f * p[2]);
    M2 Ry = {{{{c0, 0.f}, {-s0, 0.f}}, {{s0, 0.f}, {c0, 0.f}}}};
    M2 Rz = {{{{c1, -s1}, {0.f, 0.f}}, {{0.f, 0.f}, {c1, s1}}}};
    M2 Rx = {{{{c2, 0.f}, {0.f, -s2}}, {{0.f, -s2}, {c2, 0.f}}}};
    return mmul(Rx, mmul(Rz, Ry));
}

// ---------------- multi-row LDS tree reduction (256 threads, Q rows) ----------------
// (kept for tier B/C kernels)
template <int Q>
__device__ __forceinline__ void rows_reduce(float* red, const float* vals, int tid) {
#pragma unroll
    for (int q = 0; q < Q; q++) red[q * 256 + tid] = vals[q];
    __syncthreads();
#pragma unroll
    for (int s = 128; s > 0; s >>= 1) {
        for (int idx = tid; idx < Q * s; idx += 256) {
            int row = idx / s, i = idx - row * s;
            red[row * 256 + i] += red[row * 256 + i + s];
        }
        __syncthreads();
    }
}

// wave-shuffle full reduce of one value across 64 lanes
__device__ __forceinline__ float wave_sum(float v) {
#pragma unroll
    for (int off = 32; off; off >>= 1) v += __shfl_xor(v, off, 64);
    return v;
}

__global__ void zero_ws(float* ws, int n) {
    int i = blockIdx.x * blockDim.x + threadIdx.x;
    if (i < n) ws[i] = 0.f;
}

__device__ __forceinline__ float slot_sum(const float* stats, int c) {
    float s = 0.f;
#pragma unroll
    for (int sl = 0; sl < NS; sl++) s += stats[sl * SLOT_STRIDE + c];
    return s;
}

// ================= shared phase bodies =================

// conv1 item: one 16-row strip of one image. wred = 64 floats of LDS.
// Stats reduce: shfl butterfly (no barriers) + 1 barrier + 16-thread cross-wave sum.
__device__ __forceinline__ void conv1_item_body(
        int b, int strip, const float* __restrict__ x, const float* __restrict__ w,
        const float* __restrict__ bias, const bool* gp,
        float* __restrict__ stats1p, float* __restrict__ p1ext,
        float* wred, int tid, int witem) {
    int pc = tid & 127;
    int rhalf = tid >> 7;
    int r0 = strip * 16 + rhalf * 8;
    const float* xb = x + (size_t)b * H1 * W1;
    float sums[8], sqs[8], pm[8];
#pragma unroll
    for (int c = 0; c < 8; c++) { sums[c] = 0.f; sqs[c] = 0.f; }
    bool act = pc < W2;
    if (act) {
        bool cl = pc > 0, cr = pc < W2 - 1;
        const float* rp0 = xb + (size_t)r0 * W1 + 2 * pc;
        float al, am0, am1, ar, bl, bm0, bm1, br;
        if (r0 > 0) {
            const float* rp = rp0 - W1;
            float2 m = *(const float2*)rp;
            al = cl ? rp[-1] : 0.f; am0 = m.x; am1 = m.y; ar = cr ? rp[2] : 0.f;
        } else { al = 0.f; am0 = 0.f; am1 = 0.f; ar = 0.f; }
        {
            float2 m = *(const float2*)rp0;
            bl = cl ? rp0[-1] : 0.f; bm0 = m.x; bm1 = m.y; br = cr ? rp0[2] : 0.f;
        }
#pragma unroll
        for (int rr = 0; rr < 8; rr++) {
            float nl = 0.f, nm0 = 0.f, nm1 = 0.f, nr = 0.f;
            int rn = r0 + rr + 1;
            if (rn < H1) {
                const float* rp = rp0 + (size_t)(rr + 1) * W1;
                float2 m = *(const float2*)rp;
                nl = cl ? rp[-1] : 0.f; nm0 = m.x; nm1 = m.y; nr = cr ? rp[2] : 0.f;
            }
            float4 e0 = make_float4(0.f, 0.f, 0.f, 0.f);
            float4 e1 = make_float4(0.f, 0.f, 0.f, 0.f);
#pragma unroll
            for (int c = 0; c < 8; c++) {
                const float* wc = w + c * 9;
                float y0 = bias[c], y1 = bias[c];
                y0 = fmaf(wc[0], al,  y0); y0 = fmaf(wc[1], am0, y0); y0 = fmaf(wc[2], am1, y0);
                y1 = fmaf(wc[0], am0, y1); y1 = fmaf(wc[1], am1, y1); y1 = fmaf(wc[2], ar,  y1);
                y0 = fmaf(wc[3], bl,  y0); y0 = fmaf(wc[4], bm0, y0); y0 = fmaf(wc[5], bm1, y0);
                y1 = fmaf(wc[3], bm0, y1); y1 = fmaf(wc[4], bm1, y1); y1 = fmaf(wc[5], br,  y1);
                y0 = fmaf(wc[6], nl,  y0); y0 = fmaf(wc[7], nm0, y0); y0 = fmaf(wc[8], nm1, y0);
                y1 = fmaf(wc[6], nm0, y1); y1 = fmaf(wc[7], nm1, y1); y1 = fmaf(wc[8], nr,  y1);
                sums[c] += y0 + y1;
                sqs[c] = fmaf(y0, y0, fmaf(y1, y1, sqs[c]));
                float m01 = gp[c] ? fmaxf(y0, y1) : fminf(y0, y1);
                if ((rr & 1) == 0) {
                    pm[c] = m01;
                } else {
                    float e = gp[c] ? fmaxf(pm[c], m01) : fminf(pm[c], m01);
                    if (c == 0) e0.x = e; else if (c == 1) e0.y = e;
                    else if (c == 2) e0.z = e; else if (c == 3) e0.w = e;
                    else if (c == 4) e1.x = e; else if (c == 5) e1.y = e;
                    else if (c == 6) e1.z = e; else e1.w = e;
                }
            }
            if (rr & 1) {
                int pr = (r0 + rr) >> 1;
                float* dst = p1ext + ((((size_t)b * H2 + pr) * W2 + pc) << 3);
                ((float4*)dst)[0] = e0;
                ((float4*)dst)[1] = e1;
            }
            al = bl; am0 = bm0; am1 = bm1; ar = br;
            bl = nl; bm0 = nm0; bm1 = nm1; br = nr;
        }
    }
    // wave butterfly over 16 stats, then cross-wave sum via 64-float LDS
    int wv = tid >> 6, lane = tid & 63;
#pragma unroll
    for (int c = 0; c < 8; c++) { sums[c] = wave_sum(sums[c]); sqs[c] = wave_sum(sqs[c]); }
    if (lane == 0) {
#pragma unroll
        for (int c = 0; c < 8; c++) {
            wred[wv * 16 + c] = sums[c];
            wred[wv * 16 + 8 + c] = sqs[c];
        }
    }
    __syncthreads();
    if (tid < 16)
        stats1p[((size_t)witem << 4) + tid] =
            wred[tid] + wred[16 + tid] + wred[32 + tid] + wred[48 + tid];
}

// conv2 item: one 32x32 tile. h1t = 8*34*34 floats of LDS (reused for wave partials).
__device__ __forceinline__ void conv2_item_body(
        int b, int Y0, int X0, const float* __restrict__ p1ext,
        const float* sc1, const float* sh1,
        const float* __restrict__ w2, const float* __restrict__ b2,
        const float* __restrict__ g2,
        float* __restrict__ stats2p, float* __restrict__ p2ext,
        float* smem, int tid, int witem) {
    float (*h1t)[34][34] = (float(*)[34][34])smem;
    int ty = tid >> 4, tx = tid & 15;
    const float* pb = p1ext + (((size_t)b * H2) * W2 << 3);
    for (int i = tid; i < 34 * 34; i += 256) {
        int p = i / 34, q = i % 34;
        int hy = Y0 - 1 + p, hx = X0 - 1 + q;
        if (hy >= 0 && hy < H2 && hx >= 0 && hx < W2) {
            const float* cp = pb + (((size_t)hy * W2 + hx) << 3);
            float4 u = ((const float4*)cp)[0];
            float4 v = ((const float4*)cp)[1];
            h1t[0][p][q] = fmaxf(fmaf(u.x, sc1[0], sh1[0]), 0.f);
            h1t[1][p][q] = fmaxf(fmaf(u.y, sc1[1], sh1[1]), 0.f);
            h1t[2][p][q] = fmaxf(fmaf(u.z, sc1[2], sh1[2]), 0.f);
            h1t[3][p][q] = fmaxf(fmaf(u.w, sc1[3], sh1[3]), 0.f);
            h1t[4][p][q] = fmaxf(fmaf(v.x, sc1[4], sh1[4]), 0.f);
            h1t[5][p][q] = fmaxf(fmaf(v.y, sc1[5], sh1[5]), 0.f);
            h1t[6][p][q] = fmaxf(fmaf(v.z, sc1[6], sh1[6]), 0.f);
            h1t[7][p][q] = fmaxf(fmaf(v.w, sc1[7], sh1[7]), 0.f);
        } else {
#pragma unroll
            for (int c = 0; c < 8; c++) h1t[c][p][q] = 0.f;
        }
    }
    __syncthreads();
    float acc[4][2][2];
#pragma unroll
    for (int co = 0; co < 4; co++)
#pragma unroll
        for (int dy = 0; dy < 2; dy++)
#pragma unroll
            for (int dx = 0; dx < 2; dx++) acc[co][dy][dx] = b2[co];
#pragma unroll
    for (int ci = 0; ci < 8; ci++) {
        float win[4][4];
#pragma unroll
        for (int r = 0; r < 4; r++) {
            const float2* rp = (const float2*)&h1t[ci][2 * ty + r][2 * tx];
            float2 u = rp[0], v = rp[1];
            win[r][0] = u.x; win[r][1] = u.y; win[r][2] = v.x; win[r][3] = v.y;
        }
#pragma unroll
        for (int co = 0; co < 4; co++)
#pragma unroll
            for (int ky = 0; ky < 3; ky++)
#pragma unroll
                for (int kx = 0; kx < 3; kx++) {
                    float wv = w2[co * 72 + ci * 9 + ky * 3 + kx];
#pragma unroll
                    for (int dy = 0; dy < 2; dy++)
#pragma unroll
                        for (int dx = 0; dx < 2; dx++)
                            acc[co][dy][dx] = fmaf(wv, win[dy + ky][dx + kx], acc[co][dy][dx]);
                }
    }
    int cy0 = Y0 + 2 * ty, cx0 = X0 + 2 * tx;
    bool vy0 = cy0 < H2, vy1 = cy0 + 1 < H2, vx0 = cx0 < W2, vx1 = cx0 + 1 < W2;
    float vals[8];
#pragma unroll
    for (int co = 0; co < 4; co++) {
        float s = 0.f, q = 0.f;
        if (vy0 && vx0) { float a = acc[co][0][0]; s += a; q = fmaf(a, a, q); }
        if (vy0 && vx1) { float a = acc[co][0][1]; s += a; q = fmaf(a, a, q); }
        if (vy1 && vx0) { float a = acc[co][1][0]; s += a; q = fmaf(a, a, q); }
        if (vy1 && vx1) { float a = acc[co][1][1]; s += a; q = fmaf(a, a, q); }
        vals[co] = s;
        vals[4 + co] = q;
    }
    {
        int hy = (Y0 >> 1) + ty, hx = (X0 >> 1) + tx;
        if (hy < HP && hx < WP) {
#pragma unroll
            for (int co = 0; co < 4; co++) {
                float mx = fmaxf(fmaxf(acc[co][0][0], acc[co][0][1]),
                                 fmaxf(acc[co][1][0], acc[co][1][1]));
                float mn = fminf(fminf(acc[co][0][0], acc[co][0][1]),
                                 fminf(acc[co][1][0], acc[co][1][1]));
                p2ext[(((size_t)b * 4 + co) * HP + hy) * WP + hx] = (g2[co] >= 0.f) ? mx : mn;
            }
        }
    }
    // shfl-reduce 8 stats across wave, then cross-wave via 32 floats of smem
    int wv = tid >> 6, lane = tid & 63;
#pragma unroll
    for (int c = 0; c < 8; c++) vals[c] = wave_sum(vals[c]);
    __syncthreads();                  // all reads of h1t complete before overwrite
    if (lane == 0) {
#pragma unroll
        for (int c = 0; c < 8; c++) smem[wv * 8 + c] = vals[c];
    }
    __syncthreads();
    if (tid < 8)
        stats2p[((size_t)witem << 3) + tid] =
            smem[tid] + smem[8 + tid] + smem[16 + tid] + smem[24 + tid];
}

// pool item: inline stats2 reduce + BN2+relu spatial sum. Needs 1040 floats of LDS.
__device__ __forceinline__ void pool_item_body(
        int b, int co, const float* __restrict__ p2ext,
        const float* __restrict__ g2, const float* __restrict__ be2,
        const float* __restrict__ stats2p, int nblk2,
        float* __restrict__ featbuf, float N2, float* red, int tid) {
    {
        const float4* sp = (const float4*)stats2p;
        int tot4 = nblk2 << 1;
        float4 a0 = make_float4(0.f, 0.f, 0.f, 0.f);
        float4 a1 = a0;
        int idx = tid;
        for (; idx + 256 < tot4; idx += 512) {
            float4 t0 = sp[idx];
            float4 t1 = sp[idx + 256];
            a0.x += t0.x; a0.y += t0.y; a0.z += t0.z; a0.w += t0.w;
            a1.x += t1.x; a1.y += t1.y; a1.z += t1.z; a1.w += t1.w;
        }
        for (; idx < tot4; idx += 256) {
            float4 t = sp[idx];
            a0.x += t.x; a0.y += t.y; a0.z += t.z; a0.w += t.w;
        }
        a0.x += a1.x; a0.y += a1.y; a0.z += a1.z; a0.w += a1.w;
        ((float4*)red)[tid] = a0;
    }
    __syncthreads();
    if (tid < 8) {
        int hi = tid >> 2, lo = tid & 3;
        float s = 0.f;
#pragma unroll
        for (int k = 0; k < 128; k++) s += red[((hi + (k << 1)) << 2) + lo];
        red[1024 + tid] = s;
    }
    __syncthreads();
    float su = red[1024 + co], sq = red[1024 + 4 + co];
    float mu = su / N2;
    float var = sq / N2 - mu * mu;
    float sc = g2[co] * rsqrtf(var + 1e-5f);
    float sh = be2[co] - mu * sc;
    const float4* P4 = (const float4*)(p2ext + ((size_t)b * 4 + co) * (HP * WP));
    float s = 0.f;
    for (int i = tid; i < (HP * WP) / 4; i += 256) {
        float4 t = P4[i];
        s += fmaxf(fmaf(t.x, sc, sh), 0.f) + fmaxf(fmaf(t.y, sc, sh), 0.f) +
             fmaxf(fmaf(t.z, sc, sh), 0.f) + fmaxf(fmaf(t.w, sc, sh), 0.f);
    }
    // shfl reduce + 1 barrier
    s = wave_sum(s);
    __syncthreads();
    if ((tid & 63) == 0) red[tid >> 6] = s;
    __syncthreads();
    if (tid == 0) featbuf[(size_t)b * 4 + co] = red[0] + red[1] + red[2] + red[3];
}

// ---------------- batch-sum helper (block-wide, inactive lanes pass 0) ----------------
__device__ __forceinline__ float bsum(float v, float* lds) {
#pragma unroll
    for (int off = 32; off; off >>= 1) v += __shfl_xor(v, off, 64);
    __syncthreads();
    if ((threadIdx.x & 63) == 0) lds[threadIdx.x >> 6] = v;
    __syncthreads();
    float r = 0.f;
    int nw = (int)(blockDim.x + 63) >> 6;
#pragma clang loop unroll(disable)
    for (int i = 0; i < nw; i++) r += lds[i];
    return r;
}

// finalize body: guarded for blockDim >= B (inactive lanes contribute 0)
__device__ __forceinline__ void finalize_body(
        const float* __restrict__ featbuf, const float* __restrict__ theta,
        const float* __restrict__ rho, const float* __restrict__ ng,
        const float* __restrict__ nb, float* __restrict__ out, int B, float* lds) {
    int b = threadIdx.x;
    bool act = b < B;
    float f[4];
#pragma unroll
    for (int j = 0; j < 4; j++) f[j] = act ? featbuf[b * 4 + j] * (1.f / (HP * WP)) : 0.f;
    float n = 4.f * (float)B;
    float mean = bsum(f[0] + f[1] + f[2] + f[3], lds) / n;
    float d2 = 0.f;
    if (act) {
#pragma unroll
        for (int j = 0; j < 4; j++) { float d = f[j] - mean; d2 += d * d; }
    }
    float var1 = bsum(d2, lds) / (n - 1.f);
    float stdv = sqrtf(fmaxf(var1, 0.f)) + 1e-6f;
    const float PI = 3.14159265358979323846f;
    float cs[4], sn[4];
#pragma unroll
    for (int j = 0; j < 4; j++) {
        float sc = (f[j] - mean) / stdv * PI;
        cs[j] = cosf(0.5f * sc);
        sn[j] = sinf(0.5f * sc);
    }
    C2 st[16];
    {
        float amp[16];
        amp[1] = sn[3]; amp[0] = cs[3];
#pragma unroll
        for (int k = 0; k < 2; k++) { amp[k + 2] = amp[k] * sn[2]; amp[k] *= cs[2]; }
#pragma unroll
        for (int k = 0; k < 4; k++) { amp[k + 4] = amp[k] * sn[1]; amp[k] *= cs[1]; }
#pragma unroll
        for (int k = 0; k < 8; k++) { amp[k + 8] = amp[k] * sn[0]; amp[k] *= cs[0]; }
#pragma unroll
        for (int i = 0; i < 16; i++) st[i] = C2{amp[i], 0.f};
    }
#pragma clang loop unroll(disable)
    for (int l = 0; l < 2; l++) {
        const float* p = (l == 0) ? theta : rho;
#pragma clang loop unroll(disable)
        for (int i = 0; i < 4; i++) {
            M2 U = combined_u(p + i * 3);
            switch (i) {
            case 0: ap1s<8>(st, U.m[0][0], U.m[0][1], U.m[1][0], U.m[1][1]); break;
            case 1: ap1s<4>(st, U.m[0][0], U.m[0][1], U.m[1][0], U.m[1][1]); break;
            case 2: ap1s<2>(st, U.m[0][0], U.m[0][1], U.m[1][0], U.m[1][1]); break;
            default: ap1s<1>(st, U.m[0][0], U.m[0][1], U.m[1][0], U.m[1][1]); break;
            }
        }
        if (l == 0) { cnot_s<8, 4>(st); cnot_s<4, 2>(st); cnot_s<2, 1>(st); }
        else        { cnot_s<4, 8>(st); cnot_s<2, 4>(st); cnot_s<1, 2>(st); }
    }
    float e[4];
#pragma unroll
    for (int qb = 0; qb < 4; qb++) {
        int m = 8 >> qb;
        float p0 = 0.f, p1 = 0.f;
#pragma unroll
        for (int i = 0; i < 16; i++) {
            float pr = st[i].re * st[i].re + st[i].im * st[i].im;
            if (i & m) p1 += pr; else p0 += pr;
        }
        e[qb] = p0 - p1;
    }
#pragma clang loop unroll(disable)
    for (int j = 0; j < 4; j++) {
        float mu = bsum(act ? e[j] : 0.f, lds) / (float)B;
        float dv = e[j] - mu;
        float v = bsum(act ? dv * dv : 0.f, lds) / (float)B;
        if (act) out[b * 4 + j] = fmaf(dv, rsqrtf(v + 1e-5f) * ng[j], nb[j]);
    }
}

// ================= tier-A kernels (5 launches) =================

// tiny LDS + high occupancy: 8 blocks/CU (32 waves) now that the 16KB reduce buffer is gone
__global__ __launch_bounds__(256, 8) void conv1_pool_stats(
        const float* __restrict__ x, const float* __restrict__ w,
        const float* __restrict__ bias, const float* __restrict__ g1,
        float* __restrict__ stats1p, float* __restrict__ p1ext) {
    __shared__ float wred[64];
    int strip = blockIdx.x;
    int b = blockIdx.y;
    int tid = threadIdx.x;
    bool gp[8];
#pragma unroll
    for (int c = 0; c < 8; c++) gp[c] = g1[c] >= 0.f;
    conv1_item_body(b, strip, x, w, bias, gp, stats1p, p1ext, wred, tid, b * 14 + strip);
}

// 1-block kernel: reduce conv1 partials -> BN1 affine (sc1[8] | sh1[8]) in aff1.
__global__ void affine1(const float* __restrict__ stats1p, int nblk1,
                        const float* __restrict__ g1, const float* __restrict__ be1,
                        float* __restrict__ aff1, float N1) {
    __shared__ float scr[1024 + 16];
    int tid = threadIdx.x;
    const float4* sp = (const float4*)stats1p;
    int tot4 = nblk1 << 2;
    float4 a0 = make_float4(0.f, 0.f, 0.f, 0.f);
    float4 a1 = a0, a2 = a0, a3 = a0;
    int idx = tid;
    for (; idx + 768 < tot4; idx += 1024) {
        float4 t0 = sp[idx];
        float4 t1 = sp[idx + 256];
        float4 t2 = sp[idx + 512];
        float4 t3 = sp[idx + 768];
        a0.x += t0.x; a0.y += t0.y; a0.z += t0.z; a0.w += t0.w;
        a1.x += t1.x; a1.y += t1.y; a1.z += t1.z; a1.w += t1.w;
        a2.x += t2.x; a2.y += t2.y; a2.z += t2.z; a2.w += t2.w;
        a3.x += t3.x; a3.y += t3.y; a3.z += t3.z; a3.w += t3.w;
    }
    for (; idx < tot4; idx += 256) {
        float4 t = sp[idx];
        a0.x += t.x; a0.y += t.y; a0.z += t.z; a0.w += t.w;
    }
    a0.x += a1.x + a2.x + a3.x;
    a0.y += a1.y + a2.y + a3.y;
    a0.z += a1.z + a2.z + a3.z;
    a0.w += a1.w + a2.w + a3.w;
    ((float4*)scr)[tid] = a0;                // scr[4*tid+j] holds class (tid&3)*4+j
    __syncthreads();
    if (tid < 16) {
        int hi = tid >> 2, lo = tid & 3;     // class tid = 4*hi + lo
        float s = 0.f;
#pragma unroll
        for (int k = 0; k < 64; k++) s += scr[((hi + (k << 2)) << 2) + lo];
        scr[1024 + tid] = s;
    }
    __syncthreads();
    if (tid < 8) {
        float su = scr[1024 + tid], sq = scr[1024 + 8 + tid];
        float mu = su / N1;
        float var = sq / N1 - mu * mu;
        float sc = g1[tid] * rsqrtf(var + 1e-5f);
        aff1[tid] = sc;
        aff1[8 + tid] = be1[tid] - mu * sc;
    }
}

__global__ __launch_bounds__(256, 4) void conv2_stats_slim(
        const float* __restrict__ p1ext, const float* __restrict__ aff1,
        const float* __restrict__ w2, const float* __restrict__ b2,
        const float* __restrict__ g2,
        float* __restrict__ stats2p, float* __restrict__ p2ext) {
    __shared__ __align__(16) float smem[8 * 34 * 34];
    __shared__ float sc1[8], sh1[8];
    int b = blockIdx.z;
    int tid = threadIdx.y * 16 + threadIdx.x;
    if (tid < 8) { sc1[tid] = aff1[tid]; sh1[tid] = aff1[8 + tid]; }
    __syncthreads();
    int blkid = (blockIdx.z * gridDim.y + blockIdx.y) * gridDim.x + blockIdx.x;
    conv2_item_body(b, blockIdx.y * 32, blockIdx.x * 32, p1ext, sc1, sh1,
                    w2, b2, g2, stats2p, p2ext, smem, tid, blkid);
}

__global__ void pool_bn_mean_p(const float* __restrict__ p2ext,
                               const float* __restrict__ g2, const float* __restrict__ be2,
                               const float* __restrict__ stats2p, int nblk2,
                               float* __restrict__ featbuf, float N2) {
    __shared__ float red[1024 + 16];
    pool_item_body(blockIdx.x >> 2, blockIdx.x & 3, p2ext, g2, be2, stats2p, nblk2,
                   featbuf, N2, red, threadIdx.x);
}

__global__ void finalize(const float* __restrict__ featbuf, const float* __restrict__ theta,
                         const float* __restrict__ rho, const float* __restrict__ ng,
                         const float* __restrict__ nb, float* __restrict__ out, int B) {
    __shared__ float lds[16];
    finalize_body(featbuf, theta, rho, ng, nb, out, B, lds);
}

// ================= tier B/C kernels (unchanged) =================

__global__ void conv1_stats(const float* __restrict__ x, const float* __restrict__ w,
                            const float* __restrict__ bias, float* __restrict__ stats) {
    __shared__ float red[16 * 256];
    int strip = blockIdx.x;
    int b = blockIdx.y;
    int tid = threadIdx.x;
    const float* xb = x + (size_t)b * H1 * W1;
    float sums[8], sqs[8];
#pragma unroll
    for (int c = 0; c < 8; c++) { sums[c] = 0.f; sqs[c] = 0.f; }
    int col = tid;
    if (col < W1) {
        bool cl = col > 0, cr = col < W1 - 1;
        int row0 = strip * 8;
        float a0, a1, a2, b0, b1, b2, c0, c1, c2;
        {
            int r = row0 - 1;
            if (r >= 0) {
                a0 = cl ? xb[r * W1 + col - 1] : 0.f;
                a1 = xb[r * W1 + col];
                a2 = cr ? xb[r * W1 + col + 1] : 0.f;
            } else { a0 = a1 = a2 = 0.f; }
            r = row0;
            b0 = cl ? xb[r * W1 + col - 1] : 0.f;
            b1 = xb[r * W1 + col];
            b2 = cr ? xb[r * W1 + col + 1] : 0.f;
        }
        for (int rr = 0; rr < 8; rr++) {
            int rn = row0 + rr + 1;
            if (rn < H1) {
                c0 = cl ? xb[rn * W1 + col - 1] : 0.f;
                c1 = xb[rn * W1 + col];
                c2 = cr ? xb[rn * W1 + col + 1] : 0.f;
            } else { c0 = c1 = c2 = 0.f; }
#pragma unroll
            for (int c = 0; c < 8; c++) {
                float acc = bias[c];
                acc = fmaf(w[c * 9 + 0], a0, acc);
                acc = fmaf(w[c * 9 + 1], a1, acc);
                acc = fmaf(w[c * 9 + 2], a2, acc);
                acc = fmaf(w[c * 9 + 3], b0, acc);
                acc = fmaf(w[c * 9 + 4], b1, acc);
                acc = fmaf(w[c * 9 + 5], b2, acc);
                acc = fmaf(w[c * 9 + 6], c0, acc);
                acc = fmaf(w[c * 9 + 7], c1, acc);
                acc = fmaf(w[c * 9 + 8], c2, acc);
                sums[c] += acc;
                sqs[c] = fmaf(acc, acc, sqs[c]);
            }
            a0 = b0; a1 = b1; a2 = b2;
            b0 = c0; b1 = c1; b2 = c2;
        }
    }
    float vals[16];
#pragma unroll
    for (int c = 0; c < 8; c++) { vals[c] = sums[c]; vals[8 + c] = sqs[c]; }
    rows_reduce<16>(red, vals, tid);
    int slot = (b * 28 + strip) & (NS - 1);
    if (tid < 16) atomicAdd(stats + slot * SLOT_STRIDE + tid, red[tid * 256]);
}

template <int PH, int PW>
__device__ __forceinline__ void build_h1_tile(const float* __restrict__ xb,
                                              float (*h1t)[PH][PW],
                                              const float* __restrict__ w1,
                                              const float* __restrict__ b1,
                                              const float* sc1, const float* sh1,
                                              int oy0, int ox0, int tid) {
    for (int i = tid; i < PH * PW; i += 256) {
        int p = i / PW, q = i % PW;
        int hy = oy0 + p, hx = ox0 + q;
        bool ok = (hy >= 0 && hy < H2 && hx >= 0 && hx < W2);
        float xp[5][5];
        if (hy >= 1 && hy <= H2 - 2 && hx >= 1 && hx <= W2 - 2) {
            const float* bp = xb + (2 * hy - 1) * W1 + (2 * hx - 1);
#pragma unroll
            for (int r = 0; r < 5; r++)
#pragma unroll
                for (int c = 0; c < 5; c++) xp[r][c] = bp[r * W1 + c];
        } else if (ok) {
#pragma unroll
            for (int r = 0; r < 5; r++)
#pragma unroll
                for (int c = 0; c < 5; c++) {
                    int gy = 2 * hy - 1 + r, gx = 2 * hx - 1 + c;
                    xp[r][c] = (gy >= 0 && gy < H1 && gx >= 0 && gx < W1) ? xb[gy * W1 + gx] : 0.f;
                }
        }
#pragma unroll
        for (int c = 0; c < 8; c++) {
            float mx = 0.f;
            if (ok) {
                mx = -INFINITY;
#pragma unroll
                for (int dy = 0; dy < 2; dy++)
#pragma unroll
                    for (int dx = 0; dx < 2; dx++) {
                        float acc = b1[c];
#pragma unroll
                        for (int ky = 0; ky < 3; ky++)
#pragma unroll
                            for (int kx = 0; kx < 3; kx++)
                                acc = fmaf(w1[c * 9 + ky * 3 + kx], xp[dy + ky][dx + kx], acc);
                        mx = fmaxf(mx, fmaxf(fmaf(acc, sc1[c], sh1[c]), 0.f));
                    }
            }
            h1t[c][p][q] = mx;
        }
    }
}

template <bool STORE>
__global__ __launch_bounds__(256, 4) void conv2_stats_fused(
        const float* __restrict__ x, const float* __restrict__ w1,
        const float* __restrict__ b1, const float* __restrict__ g1,
        const float* __restrict__ be1, const float* __restrict__ stats1,
        const float* __restrict__ w2, const float* __restrict__ b2,
        float* __restrict__ stats2,
        float* __restrict__ pmax, float* __restrict__ pmin, float N1) {
    __shared__ __align__(16) float h1t[8][34][34];
    __shared__ float sc1[8], sh1[8];
    int b = blockIdx.z;
    int Y0 = blockIdx.y * 32, X0 = blockIdx.x * 32;
    int ty = threadIdx.y, tx = threadIdx.x;
    int tid = ty * 16 + tx;
    if (tid < 8) {
        float su = slot_sum(stats1, tid), sq = slot_sum(stats1, 8 + tid);
        float mu = su / N1;
        float var = sq / N1 - mu * mu;
        float sc = g1[tid] * rsqrtf(var + 1e-5f);
        sc1[tid] = sc;
        sh1[tid] = be1[tid] - mu * sc;
    }
    __syncthreads();
    const float* xb = x + (size_t)b * H1 * W1;
    build_h1_tile<34, 34>(xb, h1t, w1, b1, sc1, sh1, Y0 - 1, X0 - 1, tid);
    __syncthreads();
    float acc[4][2][2];
#pragma unroll
    for (int co = 0; co < 4; co++)
#pragma unroll
        for (int dy = 0; dy < 2; dy++)
#pragma unroll
            for (int dx = 0; dx < 2; dx++) acc[co][dy][dx] = b2[co];
#pragma unroll
    for (int ci = 0; ci < 8; ci++) {
        float win[4][4];
#pragma unroll
        for (int r = 0; r < 4; r++) {
            const float2* rp = (const float2*)&h1t[ci][2 * ty + r][2 * tx];
            float2 u = rp[0], v = rp[1];
            win[r][0] = u.x; win[r][1] = u.y; win[r][2] = v.x; win[r][3] = v.y;
        }
#pragma unroll
        for (int co = 0; co < 4; co++)
#pragma unroll
            for (int ky = 0; ky < 3; ky++)
#pragma unroll
                for (int kx = 0; kx < 3; kx++) {
                    float wv = w2[co * 72 + ci * 9 + ky * 3 + kx];
#pragma unroll
                    for (int dy = 0; dy < 2; dy++)
#pragma unroll
                        for (int dx = 0; dx < 2; dx++)
                            acc[co][dy][dx] = fmaf(wv, win[dy + ky][dx + kx], acc[co][dy][dx]);
                }
    }
    int cy0 = Y0 + 2 * ty, cx0 = X0 + 2 * tx;
    bool vy0 = cy0 < H2, vy1 = cy0 + 1 < H2, vx0 = cx0 < W2, vx1 = cx0 + 1 < W2;
    float vals[8];
#pragma unroll
    for (int co = 0; co < 4; co++) {
        float s = 0.f, q = 0.f;
        if (vy0 && vx0) { float a = acc[co][0][0]; s += a; q = fmaf(a, a, q); }
        if (vy0 && vx1) { float a = acc[co][0][1]; s += a; q = fmaf(a, a, q); }
        if (vy1 && vx0) { float a = acc[co][1][0]; s += a; q = fmaf(a, a, q); }
        if (vy1 && vx1) { float a = acc[co][1][1]; s += a; q = fmaf(a, a, q); }
        vals[co] = s;
        vals[4 + co] = q;
    }
    if (STORE) {
        int hy = (Y0 >> 1) + ty, hx = (X0 >> 1) + tx;
        if (hy < HP && hx < WP) {
#pragma unroll
            for (int co = 0; co < 4; co++) {
                float mx = fmaxf(fmaxf(acc[co][0][0], acc[co][0][1]),
                                 fmaxf(acc[co][1][0], acc[co][1][1]));
                float mn = fminf(fminf(acc[co][0][0], acc[co][0][1]),
                                 fminf(acc[co][1][0], acc[co][1][1]));
                size_t idx = (((size_t)b * 4 + co) * HP + hy) * WP + hx;
                pmax[idx] = mx;
                pmin[idx] = mn;
            }
        }
    }
    __syncthreads();
    float* red = (float*)h1t;
    rows_reduce<8>(red, vals, tid);
    int slot = ((b * 16) + blockIdx.y * 4 + blockIdx.x) & (NS - 1);
    if (tid < 8) atomicAdd(stats2 + slot * SLOT_STRIDE + tid, red[tid * 256]);
}

__global__ void pool_bn_mean(const float* __restrict__ pmax, const float* __restrict__ pmin,
                             const float* __restrict__ g2, const float* __restrict__ be2,
                             const float* __restrict__ stats2,
                             float* __restrict__ featbuf, float N2) {
    __shared__ float red[256];
    int co = blockIdx.x & 3;
    int b = blockIdx.x >> 2;
    int tid = threadIdx.x;
    float su = slot_sum(stats2, co), sq = slot_sum(stats2, 4 + co);
    float mu = su / N2;
    float var = sq / N2 - mu * mu;
    float sc = g2[co] * rsqrtf(var + 1e-5f);
    float sh = be2[co] - mu * sc;
    const float* P = (sc >= 0.f ? pmax : pmin) + ((size_t)b * 4 + co) * (HP * WP);
    float s = 0.f;
    for (int i = tid; i < HP * WP; i += 256) s += fmaxf(fmaf(P[i], sc, sh), 0.f);
    red[tid] = s;
    __syncthreads();
    for (int st = 128; st > 0; st >>= 1) {
        if (tid < st) red[tid] += red[tid + st];
        __syncthreads();
    }
    if (tid == 0) featbuf[(size_t)b * 4 + co] = red[0];
}

__global__ void conv2_final_fused(const float* __restrict__ x, const float* __restrict__ w1,
                                  const float* __restrict__ b1, const float* __restrict__ g1,
                                  const float* __restrict__ be1,
                                  const float* __restrict__ stats1,
                                  const float* __restrict__ w2, const float* __restrict__ b2,
                                  const float* __restrict__ g2, const float* __restrict__ be2,
                                  const float* __restrict__ stats2,
                                  float* __restrict__ featbuf, float N1, float N2) {
    __shared__ __align__(16) float h1t[8][34][34];
    __shared__ float sc1[8], sh1[8];
    __shared__ float sc2[4], sh2[4];
    int b = blockIdx.z;
    int py0 = blockIdx.y * 16, px0 = blockIdx.x * 16;
    int ty = threadIdx.y, tx = threadIdx.x;
    int tid = ty * 16 + tx;
    if (tid < 8) {
        float su = slot_sum(stats1, tid), sq = slot_sum(stats1, 8 + tid);
        float mu = su / N1;
        float var = sq / N1 - mu * mu;
        float sc = g1[tid] * rsqrtf(var + 1e-5f);
        sc1[tid] = sc;
        sh1[tid] = be1[tid] - mu * sc;
    }
    if (tid >= 16 && tid < 20) {
        int j = tid - 16;
        float su = slot_sum(stats2, j), sq = slot_sum(stats2, 4 + j);
        float mu = su / N2;
        float var = sq / N2 - mu * mu;
        float sc = g2[j] * rsqrtf(var + 1e-5f);
        sc2[j] = sc;
        sh2[j] = be2[j] - mu * sc;
    }
    __syncthreads();
    const float* xb = x + (size_t)b * H1 * W1;
    build_h1_tile<34, 34>(xb, h1t, w1, b1, sc1, sh1, 2 * py0 - 1, 2 * px0 - 1, tid);
    __syncthreads();
    bool valid = (py0 + ty < HP) && (px0 + tx < WP);
    float acc[4][2][2];
#pragma unroll
    for (int co = 0; co < 4; co++)
#pragma unroll
        for (int dy = 0; dy < 2; dy++)
#pragma unroll
            for (int dx = 0; dx < 2; dx++) acc[co][dy][dx] = b2[co];
#pragma unroll
    for (int ci = 0; ci < 8; ci++) {
        float win[4][4];
#pragma unroll
        for (int r = 0; r < 4; r++) {
            const float2* rp = (const float2*)&h1t[ci][2 * ty + r][2 * tx];
            float2 u = rp[0], v = rp[1];
            win[r][0] = u.x; win[r][1] = u.y; win[r][2] = v.x; win[r][3] = v.y;
        }
#pragma unroll
        for (int co = 0; co < 4; co++)
#pragma unroll
            for (int ky = 0; ky < 3; ky++)
#pragma unroll
                for (int kx = 0; kx < 3; kx++) {
                    float wv = w2[co * 72 + ci * 9 + ky * 3 + kx];
#pragma unroll
                    for (int dy = 0; dy < 2; dy++)
#pragma unroll
                        for (int dx = 0; dx < 2; dx++)
                            acc[co][dy][dx] = fmaf(wv, win[dy + ky][dx + kx], acc[co][dy][dx]);
                }
    }
    float vals[4];
#pragma unroll
    for (int co = 0; co < 4; co++) {
        float mx = -INFINITY;
#pragma unroll
        for (int dy = 0; dy < 2; dy++)
#pragma unroll
            for (int dx = 0; dx < 2; dx++)
                mx = fmaxf(mx, fmaxf(fmaf(acc[co][dy][dx], sc2[co], sh2[co]), 0.f));
        vals[co] = valid ? mx : 0.f;
    }
    __syncthreads();
    float* red = (float*)h1t;
    rows_reduce<4>(red, vals, tid);
    if (tid < 4) atomicAdd(featbuf + (size_t)b * 4 + tid, red[tid * 256]);
}

// ================= host launcher =================
extern "C" void kernel_launch(void* const* d_in, const int* in_sizes, int n_in,
                              void* d_out, int out_size, void* d_ws, size_t ws_size,
                              hipStream_t stream) {
    const float* x     = (const float*)d_in[0];
    const float* w1    = (const float*)d_in[1];
    const float* b1    = (const float*)d_in[2];
    const float* g1    = (const float*)d_in[3];
    const float* be1   = (const float*)d_in[4];
    const float* w2    = (const float*)d_in[5];
    const float* b2    = (const float*)d_in[6];
    const float* g2    = (const float*)d_in[7];
    const float* be2   = (const float*)d_in[8];
    const float* theta = (const float*)d_in[9];
    const float* rho   = (const float*)d_in[10];
    const float* ng    = (const float*)d_in[11];
    const float* nb    = (const float*)d_in[12];
    float* out = (float*)d_out;

    int B = in_sizes[0] / (H1 * W1);

    float N1 = (float)B * H1 * W1;
    float N2 = (float)B * H2 * W2;

    int nblk1 = 14 * B;
    int nblk2 = 16 * B;

    size_t p2n = (size_t)B * 4 * HP * WP;
    size_t p1n = (size_t)B * 8 * H2 * W2;

    // tier A layout: stats1p | stats2p | aff1[16] | featbuf | p2ext | p1ext (no pre-zero)
    size_t offs1p = 0;
    size_t offs2p = offs1p + (size_t)nblk1 * 16;
    size_t offaff = offs2p + (size_t)nblk2 * 8;
    size_t offfb  = offaff + 16;
    size_t offp2  = offfb + (size_t)B * 4;
    size_t offp1  = offp2 + p2n;
    size_t needA  = (offp1 + p1n) * sizeof(float);

    size_t common = (size_t)(2 * NS * SLOT_STRIDE) + (size_t)B * 4;
    size_t needB = (common + 2 * p2n) * sizeof(float);

    bool tierA = ws_size >= needA;                    // constant per process -> graph-safe
    bool tierB = !tierA && ws_size >= needB;

    float* ws = (float*)d_ws;

    if (tierA) {
        float* stats1p = ws + offs1p;
        float* stats2p = ws + offs2p;
        float* aff1    = ws + offaff;
        float* featbuf = ws + offfb;
        float* p2ext   = ws + offp2;
        float* p1ext   = ws + offp1;
        conv1_pool_stats<<<dim3(14, B), 256, 0, stream>>>(x, w1, b1, g1, stats1p, p1ext);
        affine1<<<1, 256, 0, stream>>>(stats1p, nblk1, g1, be1, aff1, N1);
        conv2_stats_slim<<<dim3(4, 4, B), dim3(16, 16), 0, stream>>>(
            p1ext, aff1, w2, b2, g2, stats2p, p2ext);
        pool_bn_mean_p<<<B * 4, 256, 0, stream>>>(p2ext, g2, be2, stats2p, nblk2, featbuf, N2);
        finalize<<<1, 256, 0, stream>>>(featbuf, theta, rho, ng, nb, out, B);
    } else if (tierB) {
        float* stats1 = ws;
        float* stats2 = ws + NS * SLOT_STRIDE;
        float* featbuf = ws + 2 * NS * SLOT_STRIDE;
        float* bufs = featbuf + (size_t)B * 4;
        float* pmax = bufs;
        float* pmin = bufs + p2n;
        int nz = (int)common;
        zero_ws<<<(nz + 255) / 256, 256, 0, stream>>>(ws, nz);
        conv1_stats<<<dim3(28, B), 256, 0, stream>>>(x, w1, b1, stats1);
        conv2_stats_fused<true><<<dim3(4, 4, B), dim3(16, 16), 0, stream>>>(
            x, w1, b1, g1, be1, stats1, w2, b2, stats2, pmax, pmin, N1);
        pool_bn_mean<<<B * 4, 256, 0, stream>>>(pmax, pmin, g2, be2, stats2, featbuf, N2);
        finalize<<<1, 256, 0, stream>>>(featbuf, theta, rho, ng, nb, out, B);
    } else {
        float* stats1 = ws;
        float* stats2 = ws + NS * SLOT_STRIDE;
        float* featbuf = ws + 2 * NS * SLOT_STRIDE;
        int nz = (int)common;
        zero_ws<<<(nz + 255) / 256, 256, 0, stream>>>(ws, nz);
        conv1_stats<<<dim3(28, B), 256, 0, stream>>>(x, w1, b1, stats1);
        conv2_stats_fused<false><<<dim3(4, 4, B), dim3(16, 16), 0, stream>>>(
            x, w1, b1, g1, be1, stats1, w2, b2, stats2, nullptr, nullptr, N1);
        conv2_final_fused<<<dim3(4, 4, B), dim3(16, 16), 0, stream>>>(
            x, w1, b1, g1, be1, stats1, w2, b2, g2, be2, stats2, featbuf, N1, N2);
        finalize<<<1, 256, 0, stream>>>(featbuf, theta, rho, ng, nb, out, B);
    }
}

// Round 10
// 176.274 us; speedup vs baseline: 1.4709x; 1.4709x over previous
//
#include <hip/hip_runtime.h>
#include <math.h>

#define H1 224
#define W1 224
#define H2 112
#define W2 112
#define HP 56
#define WP 56

#define NS 32
#define SLOT_STRIDE 64

// ---------------- complex helpers (quantum circuit) ----------------
struct C2 { float re, im; };
__device__ __forceinline__ C2 cmul(C2 a, C2 b) {
    return C2{fmaf(a.re, b.re, -a.im * b.im), fmaf(a.re, b.im, a.im * b.re)};
}
__device__ __forceinline__ C2 cadd(C2 a, C2 b) { return C2{a.re + b.re, a.im + b.im}; }

template <int S>
__device__ __forceinline__ void ap1s(C2* st, C2 u00, C2 u01, C2 u10, C2 u11) {
#pragma unroll
    for (int i = 0; i < 16; i++) {
        if (i & S) continue;
        C2 a0 = st[i], a1 = st[i + S];
        st[i]     = cadd(cmul(u00, a0), cmul(u01, a1));
        st[i + S] = cadd(cmul(u10, a0), cmul(u11, a1));
    }
}
template <int SC, int STT>
__device__ __forceinline__ void cnot_s(C2* st) {
#pragma unroll
    for (int i = 0; i < 16; i++)
        if ((i & SC) && !(i & STT)) { C2 t = st[i]; st[i] = st[i + STT]; st[i + STT] = t; }
}
struct M2 { C2 m[2][2]; };
__device__ __forceinline__ M2 mmul(const M2& A, const M2& B) {
    M2 R;
#pragma unroll
    for (int i = 0; i < 2; i++)
#pragma unroll
        for (int j = 0; j < 2; j++)
            R.m[i][j] = cadd(cmul(A.m[i][0], B.m[0][j]), cmul(A.m[i][1], B.m[1][j]));
    return R;
}
// combined U = Rx(p2) * Rz(p1) * Ry(p0)
__device__ __forceinline__ M2 combined_u(const float* __restrict__ p) {
    float c0 = cosf(0.5f * p[0]), s0 = sinf(0.5f * p[0]);
    float c1 = cosf(0.5f * p[1]), s1 = sinf(0.5f * p[1]);
    float c2 = cosf(0.5f * p[2]), s2 = sinf(0.5f * p[2]);
    M2 Ry = {{{{c0, 0.f}, {-s0, 0.f}}, {{s0, 0.f}, {c0, 0.f}}}};
    M2 Rz = {{{{c1, -s1}, {0.f, 0.f}}, {{0.f, 0.f}, {c1, s1}}}};
    M2 Rx = {{{{c2, 0.f}, {0.f, -s2}}, {{0.f, -s2}, {c2, 0.f}}}};
    return mmul(Rx, mmul(Rz, Ry));
}

// ---------------- multi-row LDS tree reduction (256 threads, Q rows) ----------------
// (kept for tier B/C kernels)
template <int Q>
__device__ __forceinline__ void rows_reduce(float* red, const float* vals, int tid) {
#pragma unroll
    for (int q = 0; q < Q; q++) red[q * 256 + tid] = vals[q];
    __syncthreads();
#pragma unroll
    for (int s = 128; s > 0; s >>= 1) {
        for (int idx = tid; idx < Q * s; idx += 256) {
            int row = idx / s, i = idx - row * s;
            red[row * 256 + i] += red[row * 256 + i + s];
        }
        __syncthreads();
    }
}

// wave-shuffle full reduce of one value across 64 lanes
__device__ __forceinline__ float wave_sum(float v) {
#pragma unroll
    for (int off = 32; off; off >>= 1) v += __shfl_xor(v, off, 64);
    return v;
}

__global__ void zero_ws(float* ws, int n) {
    int i = blockIdx.x * blockDim.x + threadIdx.x;
    if (i < n) ws[i] = 0.f;
}

__device__ __forceinline__ float slot_sum(const float* stats, int c) {
    float s = 0.f;
#pragma unroll
    for (int sl = 0; sl < NS; sl++) s += stats[sl * SLOT_STRIDE + c];
    return s;
}

// ================= shared phase bodies =================

// conv1 item: one 16-row strip of one image. wred = 64 floats of LDS.
// Stats reduce: shfl butterfly (no barriers) + 1 barrier + 16-thread cross-wave sum.
__device__ __forceinline__ void conv1_item_body(
        int b, int strip, const float* __restrict__ x, const float* __restrict__ w,
        const float* __restrict__ bias, const bool* gp,
        float* __restrict__ stats1p, float* __restrict__ p1ext,
        float* wred, int tid, int witem) {
    int pc = tid & 127;
    int rhalf = tid >> 7;
    int r0 = strip * 16 + rhalf * 8;
    const float* xb = x + (size_t)b * H1 * W1;
    float sums[8], sqs[8], pm[8];
#pragma unroll
    for (int c = 0; c < 8; c++) { sums[c] = 0.f; sqs[c] = 0.f; }
    bool act = pc < W2;
    if (act) {
        bool cl = pc > 0, cr = pc < W2 - 1;
        const float* rp0 = xb + (size_t)r0 * W1 + 2 * pc;
        float al, am0, am1, ar, bl, bm0, bm1, br;
        if (r0 > 0) {
            const float* rp = rp0 - W1;
            float2 m = *(const float2*)rp;
            al = cl ? rp[-1] : 0.f; am0 = m.x; am1 = m.y; ar = cr ? rp[2] : 0.f;
        } else { al = 0.f; am0 = 0.f; am1 = 0.f; ar = 0.f; }
        {
            float2 m = *(const float2*)rp0;
            bl = cl ? rp0[-1] : 0.f; bm0 = m.x; bm1 = m.y; br = cr ? rp0[2] : 0.f;
        }
#pragma unroll
        for (int rr = 0; rr < 8; rr++) {
            float nl = 0.f, nm0 = 0.f, nm1 = 0.f, nr = 0.f;
            int rn = r0 + rr + 1;
            if (rn < H1) {
                const float* rp = rp0 + (size_t)(rr + 1) * W1;
                float2 m = *(const float2*)rp;
                nl = cl ? rp[-1] : 0.f; nm0 = m.x; nm1 = m.y; nr = cr ? rp[2] : 0.f;
            }
            float4 e0 = make_float4(0.f, 0.f, 0.f, 0.f);
            float4 e1 = make_float4(0.f, 0.f, 0.f, 0.f);
#pragma unroll
            for (int c = 0; c < 8; c++) {
                const float* wc = w + c * 9;
                float y0 = bias[c], y1 = bias[c];
                y0 = fmaf(wc[0], al,  y0); y0 = fmaf(wc[1], am0, y0); y0 = fmaf(wc[2], am1, y0);
                y1 = fmaf(wc[0], am0, y1); y1 = fmaf(wc[1], am1, y1); y1 = fmaf(wc[2], ar,  y1);
                y0 = fmaf(wc[3], bl,  y0); y0 = fmaf(wc[4], bm0, y0); y0 = fmaf(wc[5], bm1, y0);
                y1 = fmaf(wc[3], bm0, y1); y1 = fmaf(wc[4], bm1, y1); y1 = fmaf(wc[5], br,  y1);
                y0 = fmaf(wc[6], nl,  y0); y0 = fmaf(wc[7], nm0, y0); y0 = fmaf(wc[8], nm1, y0);
                y1 = fmaf(wc[6], nm0, y1); y1 = fmaf(wc[7], nm1, y1); y1 = fmaf(wc[8], nr,  y1);
                sums[c] += y0 + y1;
                sqs[c] = fmaf(y0, y0, fmaf(y1, y1, sqs[c]));
                float m01 = gp[c] ? fmaxf(y0, y1) : fminf(y0, y1);
                if ((rr & 1) == 0) {
                    pm[c] = m01;
                } else {
                    float e = gp[c] ? fmaxf(pm[c], m01) : fminf(pm[c], m01);
                    if (c == 0) e0.x = e; else if (c == 1) e0.y = e;
                    else if (c == 2) e0.z = e; else if (c == 3) e0.w = e;
                    else if (c == 4) e1.x = e; else if (c == 5) e1.y = e;
                    else if (c == 6) e1.z = e; else e1.w = e;
                }
            }
            if (rr & 1) {
                int pr = (r0 + rr) >> 1;
                float* dst = p1ext + ((((size_t)b * H2 + pr) * W2 + pc) << 3);
                ((float4*)dst)[0] = e0;
                ((float4*)dst)[1] = e1;
            }
            al = bl; am0 = bm0; am1 = bm1; ar = br;
            bl = nl; bm0 = nm0; bm1 = nm1; br = nr;
        }
    }
    // wave butterfly over 16 stats, then cross-wave sum via 64-float LDS
    int wv = tid >> 6, lane = tid & 63;
#pragma unroll
    for (int c = 0; c < 8; c++) { sums[c] = wave_sum(sums[c]); sqs[c] = wave_sum(sqs[c]); }
    if (lane == 0) {
#pragma unroll
        for (int c = 0; c < 8; c++) {
            wred[wv * 16 + c] = sums[c];
            wred[wv * 16 + 8 + c] = sqs[c];
        }
    }
    __syncthreads();
    if (tid < 16)
        stats1p[((size_t)witem << 4) + tid] =
            wred[tid] + wred[16 + tid] + wred[32 + tid] + wred[48 + tid];
}

// conv2 item: one 32x32 tile. h1t = 8*34*34 floats of LDS (reused for wave partials).
__device__ __forceinline__ void conv2_item_body(
        int b, int Y0, int X0, const float* __restrict__ p1ext,
        const float* sc1, const float* sh1,
        const float* __restrict__ w2, const float* __restrict__ b2,
        const float* __restrict__ g2,
        float* __restrict__ stats2p, float* __restrict__ p2ext,
        float* smem, int tid, int witem) {
    float (*h1t)[34][34] = (float(*)[34][34])smem;
    int ty = tid >> 4, tx = tid & 15;
    const float* pb = p1ext + (((size_t)b * H2) * W2 << 3);
    for (int i = tid; i < 34 * 34; i += 256) {
        int p = i / 34, q = i % 34;
        int hy = Y0 - 1 + p, hx = X0 - 1 + q;
        if (hy >= 0 && hy < H2 && hx >= 0 && hx < W2) {
            const float* cp = pb + (((size_t)hy * W2 + hx) << 3);
            float4 u = ((const float4*)cp)[0];
            float4 v = ((const float4*)cp)[1];
            h1t[0][p][q] = fmaxf(fmaf(u.x, sc1[0], sh1[0]), 0.f);
            h1t[1][p][q] = fmaxf(fmaf(u.y, sc1[1], sh1[1]), 0.f);
            h1t[2][p][q] = fmaxf(fmaf(u.z, sc1[2], sh1[2]), 0.f);
            h1t[3][p][q] = fmaxf(fmaf(u.w, sc1[3], sh1[3]), 0.f);
            h1t[4][p][q] = fmaxf(fmaf(v.x, sc1[4], sh1[4]), 0.f);
            h1t[5][p][q] = fmaxf(fmaf(v.y, sc1[5], sh1[5]), 0.f);
            h1t[6][p][q] = fmaxf(fmaf(v.z, sc1[6], sh1[6]), 0.f);
            h1t[7][p][q] = fmaxf(fmaf(v.w, sc1[7], sh1[7]), 0.f);
        } else {
#pragma unroll
            for (int c = 0; c < 8; c++) h1t[c][p][q] = 0.f;
        }
    }
    __syncthreads();
    float acc[4][2][2];
#pragma unroll
    for (int co = 0; co < 4; co++)
#pragma unroll
        for (int dy = 0; dy < 2; dy++)
#pragma unroll
            for (int dx = 0; dx < 2; dx++) acc[co][dy][dx] = b2[co];
#pragma unroll
    for (int ci = 0; ci < 8; ci++) {
        float win[4][4];
#pragma unroll
        for (int r = 0; r < 4; r++) {
            const float2* rp = (const float2*)&h1t[ci][2 * ty + r][2 * tx];
            float2 u = rp[0], v = rp[1];
            win[r][0] = u.x; win[r][1] = u.y; win[r][2] = v.x; win[r][3] = v.y;
        }
#pragma unroll
        for (int co = 0; co < 4; co++)
#pragma unroll
            for (int ky = 0; ky < 3; ky++)
#pragma unroll
                for (int kx = 0; kx < 3; kx++) {
                    float wv = w2[co * 72 + ci * 9 + ky * 3 + kx];
#pragma unroll
                    for (int dy = 0; dy < 2; dy++)
#pragma unroll
                        for (int dx = 0; dx < 2; dx++)
                            acc[co][dy][dx] = fmaf(wv, win[dy + ky][dx + kx], acc[co][dy][dx]);
                }
    }
    int cy0 = Y0 + 2 * ty, cx0 = X0 + 2 * tx;
    bool vy0 = cy0 < H2, vy1 = cy0 + 1 < H2, vx0 = cx0 < W2, vx1 = cx0 + 1 < W2;
    float vals[8];
#pragma unroll
    for (int co = 0; co < 4; co++) {
        float s = 0.f, q = 0.f;
        if (vy0 && vx0) { float a = acc[co][0][0]; s += a; q = fmaf(a, a, q); }
        if (vy0 && vx1) { float a = acc[co][0][1]; s += a; q = fmaf(a, a, q); }
        if (vy1 && vx0) { float a = acc[co][1][0]; s += a; q = fmaf(a, a, q); }
        if (vy1 && vx1) { float a = acc[co][1][1]; s += a; q = fmaf(a, a, q); }
        vals[co] = s;
        vals[4 + co] = q;
    }
    {
        int hy = (Y0 >> 1) + ty, hx = (X0 >> 1) + tx;
        if (hy < HP && hx < WP) {
#pragma unroll
            for (int co = 0; co < 4; co++) {
                float mx = fmaxf(fmaxf(acc[co][0][0], acc[co][0][1]),
                                 fmaxf(acc[co][1][0], acc[co][1][1]));
                float mn = fminf(fminf(acc[co][0][0], acc[co][0][1]),
                                 fminf(acc[co][1][0], acc[co][1][1]));
                p2ext[(((size_t)b * 4 + co) * HP + hy) * WP + hx] = (g2[co] >= 0.f) ? mx : mn;
            }
        }
    }
    // shfl-reduce 8 stats across wave, then cross-wave via 32 floats of smem
    int wv = tid >> 6, lane = tid & 63;
#pragma unroll
    for (int c = 0; c < 8; c++) vals[c] = wave_sum(vals[c]);
    __syncthreads();                  // all reads of h1t complete before overwrite
    if (lane == 0) {
#pragma unroll
        for (int c = 0; c < 8; c++) smem[wv * 8 + c] = vals[c];
    }
    __syncthreads();
    if (tid < 8)
        stats2p[((size_t)witem << 3) + tid] =
            smem[tid] + smem[8 + tid] + smem[16 + tid] + smem[24 + tid];
}

// pool item: inline stats2 reduce + BN2+relu spatial sum. Needs 1040 floats of LDS.
__device__ __forceinline__ void pool_item_body(
        int b, int co, const float* __restrict__ p2ext,
        const float* __restrict__ g2, const float* __restrict__ be2,
        const float* __restrict__ stats2p, int nblk2,
        float* __restrict__ featbuf, float N2, float* red, int tid) {
    {
        const float4* sp = (const float4*)stats2p;
        int tot4 = nblk2 << 1;
        float4 a0 = make_float4(0.f, 0.f, 0.f, 0.f);
        float4 a1 = a0;
        int idx = tid;
        for (; idx + 256 < tot4; idx += 512) {
            float4 t0 = sp[idx];
            float4 t1 = sp[idx + 256];
            a0.x += t0.x; a0.y += t0.y; a0.z += t0.z; a0.w += t0.w;
            a1.x += t1.x; a1.y += t1.y; a1.z += t1.z; a1.w += t1.w;
        }
        for (; idx < tot4; idx += 256) {
            float4 t = sp[idx];
            a0.x += t.x; a0.y += t.y; a0.z += t.z; a0.w += t.w;
        }
        a0.x += a1.x; a0.y += a1.y; a0.z += a1.z; a0.w += a1.w;
        ((float4*)red)[tid] = a0;
    }
    __syncthreads();
    if (tid < 8) {
        int hi = tid >> 2, lo = tid & 3;
        float s = 0.f;
#pragma unroll
        for (int k = 0; k < 128; k++) s += red[((hi + (k << 1)) << 2) + lo];
        red[1024 + tid] = s;
    }
    __syncthreads();
    float su = red[1024 + co], sq = red[1024 + 4 + co];
    float mu = su / N2;
    float var = sq / N2 - mu * mu;
    float sc = g2[co] * rsqrtf(var + 1e-5f);
    float sh = be2[co] - mu * sc;
    const float4* P4 = (const float4*)(p2ext + ((size_t)b * 4 + co) * (HP * WP));
    float s = 0.f;
    for (int i = tid; i < (HP * WP) / 4; i += 256) {
        float4 t = P4[i];
        s += fmaxf(fmaf(t.x, sc, sh), 0.f) + fmaxf(fmaf(t.y, sc, sh), 0.f) +
             fmaxf(fmaf(t.z, sc, sh), 0.f) + fmaxf(fmaf(t.w, sc, sh), 0.f);
    }
    // shfl reduce + 1 barrier
    s = wave_sum(s);
    __syncthreads();
    if ((tid & 63) == 0) red[tid >> 6] = s;
    __syncthreads();
    if (tid == 0) featbuf[(size_t)b * 4 + co] = red[0] + red[1] + red[2] + red[3];
}

// ---------------- batch-sum helper (block-wide, inactive lanes pass 0) ----------------
__device__ __forceinline__ float bsum(float v, float* lds) {
#pragma unroll
    for (int off = 32; off; off >>= 1) v += __shfl_xor(v, off, 64);
    __syncthreads();
    if ((threadIdx.x & 63) == 0) lds[threadIdx.x >> 6] = v;
    __syncthreads();
    float r = 0.f;
    int nw = (int)(blockDim.x + 63) >> 6;
#pragma clang loop unroll(disable)
    for (int i = 0; i < nw; i++) r += lds[i];
    return r;
}

// finalize body: guarded for blockDim >= B (inactive lanes contribute 0)
__device__ __forceinline__ void finalize_body(
        const float* __restrict__ featbuf, const float* __restrict__ theta,
        const float* __restrict__ rho, const float* __restrict__ ng,
        const float* __restrict__ nb, float* __restrict__ out, int B, float* lds) {
    int b = threadIdx.x;
    bool act = b < B;
    float f[4];
#pragma unroll
    for (int j = 0; j < 4; j++) f[j] = act ? featbuf[b * 4 + j] * (1.f / (HP * WP)) : 0.f;
    float n = 4.f * (float)B;
    float mean = bsum(f[0] + f[1] + f[2] + f[3], lds) / n;
    float d2 = 0.f;
    if (act) {
#pragma unroll
        for (int j = 0; j < 4; j++) { float d = f[j] - mean; d2 += d * d; }
    }
    float var1 = bsum(d2, lds) / (n - 1.f);
    float stdv = sqrtf(fmaxf(var1, 0.f)) + 1e-6f;
    const float PI = 3.14159265358979323846f;
    float cs[4], sn[4];
#pragma unroll
    for (int j = 0; j < 4; j++) {
        float sc = (f[j] - mean) / stdv * PI;
        cs[j] = cosf(0.5f * sc);
        sn[j] = sinf(0.5f * sc);
    }
    C2 st[16];
    {
        float amp[16];
        amp[1] = sn[3]; amp[0] = cs[3];
#pragma unroll
        for (int k = 0; k < 2; k++) { amp[k + 2] = amp[k] * sn[2]; amp[k] *= cs[2]; }
#pragma unroll
        for (int k = 0; k < 4; k++) { amp[k + 4] = amp[k] * sn[1]; amp[k] *= cs[1]; }
#pragma unroll
        for (int k = 0; k < 8; k++) { amp[k + 8] = amp[k] * sn[0]; amp[k] *= cs[0]; }
#pragma unroll
        for (int i = 0; i < 16; i++) st[i] = C2{amp[i], 0.f};
    }
#pragma clang loop unroll(disable)
    for (int l = 0; l < 2; l++) {
        const float* p = (l == 0) ? theta : rho;
#pragma clang loop unroll(disable)
        for (int i = 0; i < 4; i++) {
            M2 U = combined_u(p + i * 3);
            switch (i) {
            case 0: ap1s<8>(st, U.m[0][0], U.m[0][1], U.m[1][0], U.m[1][1]); break;
            case 1: ap1s<4>(st, U.m[0][0], U.m[0][1], U.m[1][0], U.m[1][1]); break;
            case 2: ap1s<2>(st, U.m[0][0], U.m[0][1], U.m[1][0], U.m[1][1]); break;
            default: ap1s<1>(st, U.m[0][0], U.m[0][1], U.m[1][0], U.m[1][1]); break;
            }
        }
        if (l == 0) { cnot_s<8, 4>(st); cnot_s<4, 2>(st); cnot_s<2, 1>(st); }
        else        { cnot_s<4, 8>(st); cnot_s<2, 4>(st); cnot_s<1, 2>(st); }
    }
    float e[4];
#pragma unroll
    for (int qb = 0; qb < 4; qb++) {
        int m = 8 >> qb;
        float p0 = 0.f, p1 = 0.f;
#pragma unroll
        for (int i = 0; i < 16; i++) {
            float pr = st[i].re * st[i].re + st[i].im * st[i].im;
            if (i & m) p1 += pr; else p0 += pr;
        }
        e[qb] = p0 - p1;
    }
#pragma clang loop unroll(disable)
    for (int j = 0; j < 4; j++) {
        float mu = bsum(act ? e[j] : 0.f, lds) / (float)B;
        float dv = e[j] - mu;
        float v = bsum(act ? dv * dv : 0.f, lds) / (float)B;
        if (act) out[b * 4 + j] = fmaf(dv, rsqrtf(v + 1e-5f) * ng[j], nb[j]);
    }
}

// ================= tier-A kernels (5 launches) =================

// min-waves 4 (VGPR cap 128 >> ~50 live; no spills). LDS 512B so runtime occupancy
// can still reach 8 blocks/CU if the allocator lands <=64 VGPRs on its own.
__global__ __launch_bounds__(256, 4) void conv1_pool_stats(
        const float* __restrict__ x, const float* __restrict__ w,
        const float* __restrict__ bias, const float* __restrict__ g1,
        float* __restrict__ stats1p, float* __restrict__ p1ext) {
    __shared__ float wred[64];
    int strip = blockIdx.x;
    int b = blockIdx.y;
    int tid = threadIdx.x;
    bool gp[8];
#pragma unroll
    for (int c = 0; c < 8; c++) gp[c] = g1[c] >= 0.f;
    conv1_item_body(b, strip, x, w, bias, gp, stats1p, p1ext, wred, tid, b * 14 + strip);
}

// 1-block kernel: reduce conv1 partials -> BN1 affine (sc1[8] | sh1[8]) in aff1.
__global__ void affine1(const float* __restrict__ stats1p, int nblk1,
                        const float* __restrict__ g1, const float* __restrict__ be1,
                        float* __restrict__ aff1, float N1) {
    __shared__ float scr[1024 + 16];
    int tid = threadIdx.x;
    const float4* sp = (const float4*)stats1p;
    int tot4 = nblk1 << 2;
    float4 a0 = make_float4(0.f, 0.f, 0.f, 0.f);
    float4 a1 = a0, a2 = a0, a3 = a0;
    int idx = tid;
    for (; idx + 768 < tot4; idx += 1024) {
        float4 t0 = sp[idx];
        float4 t1 = sp[idx + 256];
        float4 t2 = sp[idx + 512];
        float4 t3 = sp[idx + 768];
        a0.x += t0.x; a0.y += t0.y; a0.z += t0.z; a0.w += t0.w;
        a1.x += t1.x; a1.y += t1.y; a1.z += t1.z; a1.w += t1.w;
        a2.x += t2.x; a2.y += t2.y; a2.z += t2.z; a2.w += t2.w;
        a3.x += t3.x; a3.y += t3.y; a3.z += t3.z; a3.w += t3.w;
    }
    for (; idx < tot4; idx += 256) {
        float4 t = sp[idx];
        a0.x += t.x; a0.y += t.y; a0.z += t.z; a0.w += t.w;
    }
    a0.x += a1.x + a2.x + a3.x;
    a0.y += a1.y + a2.y + a3.y;
    a0.z += a1.z + a2.z + a3.z;
    a0.w += a1.w + a2.w + a3.w;
    ((float4*)scr)[tid] = a0;                // scr[4*tid+j] holds class (tid&3)*4+j
    __syncthreads();
    if (tid < 16) {
        int hi = tid >> 2, lo = tid & 3;     // class tid = 4*hi + lo
        float s = 0.f;
#pragma unroll
        for (int k = 0; k < 64; k++) s += scr[((hi + (k << 2)) << 2) + lo];
        scr[1024 + tid] = s;
    }
    __syncthreads();
    if (tid < 8) {
        float su = scr[1024 + tid], sq = scr[1024 + 8 + tid];
        float mu = su / N1;
        float var = sq / N1 - mu * mu;
        float sc = g1[tid] * rsqrtf(var + 1e-5f);
        aff1[tid] = sc;
        aff1[8 + tid] = be1[tid] - mu * sc;
    }
}

__global__ __launch_bounds__(256, 4) void conv2_stats_slim(
        const float* __restrict__ p1ext, const float* __restrict__ aff1,
        const float* __restrict__ w2, const float* __restrict__ b2,
        const float* __restrict__ g2,
        float* __restrict__ stats2p, float* __restrict__ p2ext) {
    __shared__ __align__(16) float smem[8 * 34 * 34];
    __shared__ float sc1[8], sh1[8];
    int b = blockIdx.z;
    int tid = threadIdx.y * 16 + threadIdx.x;
    if (tid < 8) { sc1[tid] = aff1[tid]; sh1[tid] = aff1[8 + tid]; }
    __syncthreads();
    int blkid = (blockIdx.z * gridDim.y + blockIdx.y) * gridDim.x + blockIdx.x;
    conv2_item_body(b, blockIdx.y * 32, blockIdx.x * 32, p1ext, sc1, sh1,
                    w2, b2, g2, stats2p, p2ext, smem, tid, blkid);
}

__global__ void pool_bn_mean_p(const float* __restrict__ p2ext,
                               const float* __restrict__ g2, const float* __restrict__ be2,
                               const float* __restrict__ stats2p, int nblk2,
                               float* __restrict__ featbuf, float N2) {
    __shared__ float red[1024 + 16];
    pool_item_body(blockIdx.x >> 2, blockIdx.x & 3, p2ext, g2, be2, stats2p, nblk2,
                   featbuf, N2, red, threadIdx.x);
}

__global__ void finalize(const float* __restrict__ featbuf, const float* __restrict__ theta,
                         const float* __restrict__ rho, const float* __restrict__ ng,
                         const float* __restrict__ nb, float* __restrict__ out, int B) {
    __shared__ float lds[16];
    finalize_body(featbuf, theta, rho, ng, nb, out, B, lds);
}

// ================= tier B/C kernels (unchanged) =================

__global__ void conv1_stats(const float* __restrict__ x, const float* __restrict__ w,
                            const float* __restrict__ bias, float* __restrict__ stats) {
    __shared__ float red[16 * 256];
    int strip = blockIdx.x;
    int b = blockIdx.y;
    int tid = threadIdx.x;
    const float* xb = x + (size_t)b * H1 * W1;
    float sums[8], sqs[8];
#pragma unroll
    for (int c = 0; c < 8; c++) { sums[c] = 0.f; sqs[c] = 0.f; }
    int col = tid;
    if (col < W1) {
        bool cl = col > 0, cr = col < W1 - 1;
        int row0 = strip * 8;
        float a0, a1, a2, b0, b1, b2, c0, c1, c2;
        {
            int r = row0 - 1;
            if (r >= 0) {
                a0 = cl ? xb[r * W1 + col - 1] : 0.f;
                a1 = xb[r * W1 + col];
                a2 = cr ? xb[r * W1 + col + 1] : 0.f;
            } else { a0 = a1 = a2 = 0.f; }
            r = row0;
            b0 = cl ? xb[r * W1 + col - 1] : 0.f;
            b1 = xb[r * W1 + col];
            b2 = cr ? xb[r * W1 + col + 1] : 0.f;
        }
        for (int rr = 0; rr < 8; rr++) {
            int rn = row0 + rr + 1;
            if (rn < H1) {
                c0 = cl ? xb[rn * W1 + col - 1] : 0.f;
                c1 = xb[rn * W1 + col];
                c2 = cr ? xb[rn * W1 + col + 1] : 0.f;
            } else { c0 = c1 = c2 = 0.f; }
#pragma unroll
            for (int c = 0; c < 8; c++) {
                float acc = bias[c];
                acc = fmaf(w[c * 9 + 0], a0, acc);
                acc = fmaf(w[c * 9 + 1], a1, acc);
                acc = fmaf(w[c * 9 + 2], a2, acc);
                acc = fmaf(w[c * 9 + 3], b0, acc);
                acc = fmaf(w[c * 9 + 4], b1, acc);
                acc = fmaf(w[c * 9 + 5], b2, acc);
                acc = fmaf(w[c * 9 + 6], c0, acc);
                acc = fmaf(w[c * 9 + 7], c1, acc);
                acc = fmaf(w[c * 9 + 8], c2, acc);
                sums[c] += acc;
                sqs[c] = fmaf(acc, acc, sqs[c]);
            }
            a0 = b0; a1 = b1; a2 = b2;
            b0 = c0; b1 = c1; b2 = c2;
        }
    }
    float vals[16];
#pragma unroll
    for (int c = 0; c < 8; c++) { vals[c] = sums[c]; vals[8 + c] = sqs[c]; }
    rows_reduce<16>(red, vals, tid);
    int slot = (b * 28 + strip) & (NS - 1);
    if (tid < 16) atomicAdd(stats + slot * SLOT_STRIDE + tid, red[tid * 256]);
}

template <int PH, int PW>
__device__ __forceinline__ void build_h1_tile(const float* __restrict__ xb,
                                              float (*h1t)[PH][PW],
                                              const float* __restrict__ w1,
                                              const float* __restrict__ b1,
                                              const float* sc1, const float* sh1,
                                              int oy0, int ox0, int tid) {
    for (int i = tid; i < PH * PW; i += 256) {
        int p = i / PW, q = i % PW;
        int hy = oy0 + p, hx = ox0 + q;
        bool ok = (hy >= 0 && hy < H2 && hx >= 0 && hx < W2);
        float xp[5][5];
        if (hy >= 1 && hy <= H2 - 2 && hx >= 1 && hx <= W2 - 2) {
            const float* bp = xb + (2 * hy - 1) * W1 + (2 * hx - 1);
#pragma unroll
            for (int r = 0; r < 5; r++)
#pragma unroll
                for (int c = 0; c < 5; c++) xp[r][c] = bp[r * W1 + c];
        } else if (ok) {
#pragma unroll
            for (int r = 0; r < 5; r++)
#pragma unroll
                for (int c = 0; c < 5; c++) {
                    int gy = 2 * hy - 1 + r, gx = 2 * hx - 1 + c;
                    xp[r][c] = (gy >= 0 && gy < H1 && gx >= 0 && gx < W1) ? xb[gy * W1 + gx] : 0.f;
                }
        }
#pragma unroll
        for (int c = 0; c < 8; c++) {
            float mx = 0.f;
            if (ok) {
                mx = -INFINITY;
#pragma unroll
                for (int dy = 0; dy < 2; dy++)
#pragma unroll
                    for (int dx = 0; dx < 2; dx++) {
                        float acc = b1[c];
#pragma unroll
                        for (int ky = 0; ky < 3; ky++)
#pragma unroll
                            for (int kx = 0; kx < 3; kx++)
                                acc = fmaf(w1[c * 9 + ky * 3 + kx], xp[dy + ky][dx + kx], acc);
                        mx = fmaxf(mx, fmaxf(fmaf(acc, sc1[c], sh1[c]), 0.f));
                    }
            }
            h1t[c][p][q] = mx;
        }
    }
}

template <bool STORE>
__global__ __launch_bounds__(256, 4) void conv2_stats_fused(
        const float* __restrict__ x, const float* __restrict__ w1,
        const float* __restrict__ b1, const float* __restrict__ g1,
        const float* __restrict__ be1, const float* __restrict__ stats1,
        const float* __restrict__ w2, const float* __restrict__ b2,
        float* __restrict__ stats2,
        float* __restrict__ pmax, float* __restrict__ pmin, float N1) {
    __shared__ __align__(16) float h1t[8][34][34];
    __shared__ float sc1[8], sh1[8];
    int b = blockIdx.z;
    int Y0 = blockIdx.y * 32, X0 = blockIdx.x * 32;
    int ty = threadIdx.y, tx = threadIdx.x;
    int tid = ty * 16 + tx;
    if (tid < 8) {
        float su = slot_sum(stats1, tid), sq = slot_sum(stats1, 8 + tid);
        float mu = su / N1;
        float var = sq / N1 - mu * mu;
        float sc = g1[tid] * rsqrtf(var + 1e-5f);
        sc1[tid] = sc;
        sh1[tid] = be1[tid] - mu * sc;
    }
    __syncthreads();
    const float* xb = x + (size_t)b * H1 * W1;
    build_h1_tile<34, 34>(xb, h1t, w1, b1, sc1, sh1, Y0 - 1, X0 - 1, tid);
    __syncthreads();
    float acc[4][2][2];
#pragma unroll
    for (int co = 0; co < 4; co++)
#pragma unroll
        for (int dy = 0; dy < 2; dy++)
#pragma unroll
            for (int dx = 0; dx < 2; dx++) acc[co][dy][dx] = b2[co];
#pragma unroll
    for (int ci = 0; ci < 8; ci++) {
        float win[4][4];
#pragma unroll
        for (int r = 0; r < 4; r++) {
            const float2* rp = (const float2*)&h1t[ci][2 * ty + r][2 * tx];
            float2 u = rp[0], v = rp[1];
            win[r][0] = u.x; win[r][1] = u.y; win[r][2] = v.x; win[r][3] = v.y;
        }
#pragma unroll
        for (int co = 0; co < 4; co++)
#pragma unroll
            for (int ky = 0; ky < 3; ky++)
#pragma unroll
                for (int kx = 0; kx < 3; kx++) {
                    float wv = w2[co * 72 + ci * 9 + ky * 3 + kx];
#pragma unroll
                    for (int dy = 0; dy < 2; dy++)
#pragma unroll
                        for (int dx = 0; dx < 2; dx++)
                            acc[co][dy][dx] = fmaf(wv, win[dy + ky][dx + kx], acc[co][dy][dx]);
                }
    }
    int cy0 = Y0 + 2 * ty, cx0 = X0 + 2 * tx;
    bool vy0 = cy0 < H2, vy1 = cy0 + 1 < H2, vx0 = cx0 < W2, vx1 = cx0 + 1 < W2;
    float vals[8];
#pragma unroll
    for (int co = 0; co < 4; co++) {
        float s = 0.f, q = 0.f;
        if (vy0 && vx0) { float a = acc[co][0][0]; s += a; q = fmaf(a, a, q); }
        if (vy0 && vx1) { float a = acc[co][0][1]; s += a; q = fmaf(a, a, q); }
        if (vy1 && vx0) { float a = acc[co][1][0]; s += a; q = fmaf(a, a, q); }
        if (vy1 && vx1) { float a = acc[co][1][1]; s += a; q = fmaf(a, a, q); }
        vals[co] = s;
        vals[4 + co] = q;
    }
    if (STORE) {
        int hy = (Y0 >> 1) + ty, hx = (X0 >> 1) + tx;
        if (hy < HP && hx < WP) {
#pragma unroll
            for (int co = 0; co < 4; co++) {
                float mx = fmaxf(fmaxf(acc[co][0][0], acc[co][0][1]),
                                 fmaxf(acc[co][1][0], acc[co][1][1]));
                float mn = fminf(fminf(acc[co][0][0], acc[co][0][1]),
                                 fminf(acc[co][1][0], acc[co][1][1]));
                size_t idx = (((size_t)b * 4 + co) * HP + hy) * WP + hx;
                pmax[idx] = mx;
                pmin[idx] = mn;
            }
        }
    }
    __syncthreads();
    float* red = (float*)h1t;
    rows_reduce<8>(red, vals, tid);
    int slot = ((b * 16) + blockIdx.y * 4 + blockIdx.x) & (NS - 1);
    if (tid < 8) atomicAdd(stats2 + slot * SLOT_STRIDE + tid, red[tid * 256]);
}

__global__ void pool_bn_mean(const float* __restrict__ pmax, const float* __restrict__ pmin,
                             const float* __restrict__ g2, const float* __restrict__ be2,
                             const float* __restrict__ stats2,
                             float* __restrict__ featbuf, float N2) {
    __shared__ float red[256];
    int co = blockIdx.x & 3;
    int b = blockIdx.x >> 2;
    int tid = threadIdx.x;
    float su = slot_sum(stats2, co), sq = slot_sum(stats2, 4 + co);
    float mu = su / N2;
    float var = sq / N2 - mu * mu;
    float sc = g2[co] * rsqrtf(var + 1e-5f);
    float sh = be2[co] - mu * sc;
    const float* P = (sc >= 0.f ? pmax : pmin) + ((size_t)b * 4 + co) * (HP * WP);
    float s = 0.f;
    for (int i = tid; i < HP * WP; i += 256) s += fmaxf(fmaf(P[i], sc, sh), 0.f);
    red[tid] = s;
    __syncthreads();
    for (int st = 128; st > 0; st >>= 1) {
        if (tid < st) red[tid] += red[tid + st];
        __syncthreads();
    }
    if (tid == 0) featbuf[(size_t)b * 4 + co] = red[0];
}

__global__ void conv2_final_fused(const float* __restrict__ x, const float* __restrict__ w1,
                                  const float* __restrict__ b1, const float* __restrict__ g1,
                                  const float* __restrict__ be1,
                                  const float* __restrict__ stats1,
                                  const float* __restrict__ w2, const float* __restrict__ b2,
                                  const float* __restrict__ g2, const float* __restrict__ be2,
                                  const float* __restrict__ stats2,
                                  float* __restrict__ featbuf, float N1, float N2) {
    __shared__ __align__(16) float h1t[8][34][34];
    __shared__ float sc1[8], sh1[8];
    __shared__ float sc2[4], sh2[4];
    int b = blockIdx.z;
    int py0 = blockIdx.y * 16, px0 = blockIdx.x * 16;
    int ty = threadIdx.y, tx = threadIdx.x;
    int tid = ty * 16 + tx;
    if (tid < 8) {
        float su = slot_sum(stats1, tid), sq = slot_sum(stats1, 8 + tid);
        float mu = su / N1;
        float var = sq / N1 - mu * mu;
        float sc = g1[tid] * rsqrtf(var + 1e-5f);
        sc1[tid] = sc;
        sh1[tid] = be1[tid] - mu * sc;
    }
    if (tid >= 16 && tid < 20) {
        int j = tid - 16;
        float su = slot_sum(stats2, j), sq = slot_sum(stats2, 4 + j);
        float mu = su / N2;
        float var = sq / N2 - mu * mu;
        float sc = g2[j] * rsqrtf(var + 1e-5f);
        sc2[j] = sc;
        sh2[j] = be2[j] - mu * sc;
    }
    __syncthreads();
    const float* xb = x + (size_t)b * H1 * W1;
    build_h1_tile<34, 34>(xb, h1t, w1, b1, sc1, sh1, 2 * py0 - 1, 2 * px0 - 1, tid);
    __syncthreads();
    bool valid = (py0 + ty < HP) && (px0 + tx < WP);
    float acc[4][2][2];
#pragma unroll
    for (int co = 0; co < 4; co++)
#pragma unroll
        for (int dy = 0; dy < 2; dy++)
#pragma unroll
            for (int dx = 0; dx < 2; dx++) acc[co][dy][dx] = b2[co];
#pragma unroll
    for (int ci = 0; ci < 8; ci++) {
        float win[4][4];
#pragma unroll
        for (int r = 0; r < 4; r++) {
            const float2* rp = (const float2*)&h1t[ci][2 * ty + r][2 * tx];
            float2 u = rp[0], v = rp[1];
            win[r][0] = u.x; win[r][1] = u.y; win[r][2] = v.x; win[r][3] = v.y;
        }
#pragma unroll
        for (int co = 0; co < 4; co++)
#pragma unroll
            for (int ky = 0; ky < 3; ky++)
#pragma unroll
                for (int kx = 0; kx < 3; kx++) {
                    float wv = w2[co * 72 + ci * 9 + ky * 3 + kx];
#pragma unroll
                    for (int dy = 0; dy < 2; dy++)
#pragma unroll
                        for (int dx = 0; dx < 2; dx++)
                            acc[co][dy][dx] = fmaf(wv, win[dy + ky][dx + kx], acc[co][dy][dx]);
                }
    }
    float vals[4];
#pragma unroll
    for (int co = 0; co < 4; co++) {
        float mx = -INFINITY;
#pragma unroll
        for (int dy = 0; dy < 2; dy++)
#pragma unroll
            for (int dx = 0; dx < 2; dx++)
                mx = fmaxf(mx, fmaxf(fmaf(acc[co][dy][dx], sc2[co], sh2[co]), 0.f));
        vals[co] = valid ? mx : 0.f;
    }
    __syncthreads();
    float* red = (float*)h1t;
    rows_reduce<4>(red, vals, tid);
    if (tid < 4) atomicAdd(featbuf + (size_t)b * 4 + tid, red[tid * 256]);
}

// ================= host launcher =================
extern "C" void kernel_launch(void* const* d_in, const int* in_sizes, int n_in,
                              void* d_out, int out_size, void* d_ws, size_t ws_size,
                              hipStream_t stream) {
    const float* x     = (const float*)d_in[0];
    const float* w1    = (const float*)d_in[1];
    const float* b1    = (const float*)d_in[2];
    const float* g1    = (const float*)d_in[3];
    const float* be1   = (const float*)d_in[4];
    const float* w2    = (const float*)d_in[5];
    const float* b2    = (const float*)d_in[6];
    const float* g2    = (const float*)d_in[7];
    const float* be2   = (const float*)d_in[8];
    const float* theta = (const float*)d_in[9];
    const float* rho   = (const float*)d_in[10];
    const float* ng    = (const float*)d_in[11];
    const float* nb    = (const float*)d_in[12];
    float* out = (float*)d_out;

    int B = in_sizes[0] / (H1 * W1);

    float N1 = (float)B * H1 * W1;
    float N2 = (float)B * H2 * W2;

    int nblk1 = 14 * B;
    int nblk2 = 16 * B;

    size_t p2n = (size_t)B * 4 * HP * WP;
    size_t p1n = (size_t)B * 8 * H2 * W2;

    // tier A layout: stats1p | stats2p | aff1[16] | featbuf | p2ext | p1ext (no pre-zero)
    size_t offs1p = 0;
    size_t offs2p = offs1p + (size_t)nblk1 * 16;
    size_t offaff = offs2p + (size_t)nblk2 * 8;
    size_t offfb  = offaff + 16;
    size_t offp2  = offfb + (size_t)B * 4;
    size_t offp1  = offp2 + p2n;
    size_t needA  = (offp1 + p1n) * sizeof(float);

    size_t common = (size_t)(2 * NS * SLOT_STRIDE) + (size_t)B * 4;
    size_t needB = (common + 2 * p2n) * sizeof(float);

    bool tierA = ws_size >= needA;                    // constant per process -> graph-safe
    bool tierB = !tierA && ws_size >= needB;

    float* ws = (float*)d_ws;

    if (tierA) {
        float* stats1p = ws + offs1p;
        float* stats2p = ws + offs2p;
        float* aff1    = ws + offaff;
        float* featbuf = ws + offfb;
        float* p2ext   = ws + offp2;
        float* p1ext   = ws + offp1;
        conv1_pool_stats<<<dim3(14, B), 256, 0, stream>>>(x, w1, b1, g1, stats1p, p1ext);
        affine1<<<1, 256, 0, stream>>>(stats1p, nblk1, g1, be1, aff1, N1);
        conv2_stats_slim<<<dim3(4, 4, B), dim3(16, 16), 0, stream>>>(
            p1ext, aff1, w2, b2, g2, stats2p, p2ext);
        pool_bn_mean_p<<<B * 4, 256, 0, stream>>>(p2ext, g2, be2, stats2p, nblk2, featbuf, N2);
        finalize<<<1, 256, 0, stream>>>(featbuf, theta, rho, ng, nb, out, B);
    } else if (tierB) {
        float* stats1 = ws;
        float* stats2 = ws + NS * SLOT_STRIDE;
        float* featbuf = ws + 2 * NS * SLOT_STRIDE;
        float* bufs = featbuf + (size_t)B * 4;
        float* pmax = bufs;
        float* pmin = bufs + p2n;
        int nz = (int)common;
        zero_ws<<<(nz + 255) / 256, 256, 0, stream>>>(ws, nz);
        conv1_stats<<<dim3(28, B), 256, 0, stream>>>(x, w1, b1, stats1);
        conv2_stats_fused<true><<<dim3(4, 4, B), dim3(16, 16), 0, stream>>>(
            x, w1, b1, g1, be1, stats1, w2, b2, stats2, pmax, pmin, N1);
        pool_bn_mean<<<B * 4, 256, 0, stream>>>(pmax, pmin, g2, be2, stats2, featbuf, N2);
        finalize<<<1, 256, 0, stream>>>(featbuf, theta, rho, ng, nb, out, B);
    } else {
        float* stats1 = ws;
        float* stats2 = ws + NS * SLOT_STRIDE;
        float* featbuf = ws + 2 * NS * SLOT_STRIDE;
        int nz = (int)common;
        zero_ws<<<(nz + 255) / 256, 256, 0, stream>>>(ws, nz);
        conv1_stats<<<dim3(28, B), 256, 0, stream>>>(x, w1, b1, stats1);
        conv2_stats_fused<false><<<dim3(4, 4, B), dim3(16, 16), 0, stream>>>(
            x, w1, b1, g1, be1, stats1, w2, b2, stats2, nullptr, nullptr, N1);
        conv2_final_fused<<<dim3(4, 4, B), dim3(16, 16), 0, stream>>>(
            x, w1, b1, g1, be1, stats1, w2, b2, g2, be2, stats2, featbuf, N1, N2);
        finalize<<<1, 256, 0, stream>>>(featbuf, theta, rho, ng, nb, out, B);
    }
}

// Round 11
// 170.910 us; speedup vs baseline: 1.5170x; 1.0314x over previous
//
#include <hip/hip_runtime.h>
#include <math.h>

#define H1 224
#define W1 224
#define H2 112
#define W2 112
#define HP 56
#define WP 56

#define NS 32
#define SLOT_STRIDE 64

// ---------------- complex helpers (quantum circuit) ----------------
struct C2 { float re, im; };
__device__ __forceinline__ C2 cmul(C2 a, C2 b) {
    return C2{fmaf(a.re, b.re, -a.im * b.im), fmaf(a.re, b.im, a.im * b.re)};
}
__device__ __forceinline__ C2 cadd(C2 a, C2 b) { return C2{a.re + b.re, a.im + b.im}; }

template <int S>
__device__ __forceinline__ void ap1s(C2* st, C2 u00, C2 u01, C2 u10, C2 u11) {
#pragma unroll
    for (int i = 0; i < 16; i++) {
        if (i & S) continue;
        C2 a0 = st[i], a1 = st[i + S];
        st[i]     = cadd(cmul(u00, a0), cmul(u01, a1));
        st[i + S] = cadd(cmul(u10, a0), cmul(u11, a1));
    }
}
template <int SC, int STT>
__device__ __forceinline__ void cnot_s(C2* st) {
#pragma unroll
    for (int i = 0; i < 16; i++)
        if ((i & SC) && !(i & STT)) { C2 t = st[i]; st[i] = st[i + STT]; st[i + STT] = t; }
}
struct M2 { C2 m[2][2]; };
__device__ __forceinline__ M2 mmul(const M2& A, const M2& B) {
    M2 R;
#pragma unroll
    for (int i = 0; i < 2; i++)
#pragma unroll
        for (int j = 0; j < 2; j++)
            R.m[i][j] = cadd(cmul(A.m[i][0], B.m[0][j]), cmul(A.m[i][1], B.m[1][j]));
    return R;
}
// combined U = Rx(p2) * Rz(p1) * Ry(p0)
__device__ __forceinline__ M2 combined_u(const float* __restrict__ p) {
    float c0 = cosf(0.5f * p[0]), s0 = sinf(0.5f * p[0]);
    float c1 = cosf(0.5f * p[1]), s1 = sinf(0.5f * p[1]);
    float c2 = cosf(0.5f * p[2]), s2 = sinf(0.5f * p[2]);
    M2 Ry = {{{{c0, 0.f}, {-s0, 0.f}}, {{s0, 0.f}, {c0, 0.f}}}};
    M2 Rz = {{{{c1, -s1}, {0.f, 0.f}}, {{0.f, 0.f}, {c1, s1}}}};
    M2 Rx = {{{{c2, 0.f}, {0.f, -s2}}, {{0.f, -s2}, {c2, 0.f}}}};
    return mmul(Rx, mmul(Rz, Ry));
}

// ---------------- multi-row LDS tree reduction (256 threads, Q rows) ----------------
template <int Q>
__device__ __forceinline__ void rows_reduce(float* red, const float* vals, int tid) {
#pragma unroll
    for (int q = 0; q < Q; q++) red[q * 256 + tid] = vals[q];
    __syncthreads();
#pragma unroll
    for (int s = 128; s > 0; s >>= 1) {
        for (int idx = tid; idx < Q * s; idx += 256) {
            int row = idx / s, i = idx - row * s;
            red[row * 256 + i] += red[row * 256 + i + s];
        }
        __syncthreads();
    }
}

__global__ void zero_ws(float* ws, int n) {
    int i = blockIdx.x * blockDim.x + threadIdx.x;
    if (i < n) ws[i] = 0.f;
}

__device__ __forceinline__ float slot_sum(const float* stats, int c) {
    float s = 0.f;
#pragma unroll
    for (int sl = 0; sl < NS; sl++) s += stats[sl * SLOT_STRIDE + c];
    return s;
}

// ================= shared phase bodies =================

// conv1 item: one 16-row strip of one image. Needs red = 16*256 floats of LDS.
// NOTE (R9/R10 lesson): ~50 live floats -> any occupancy target >4 waves/SIMD spills
// to scratch (HBM) and costs 3x. Keep (256,2) + rows_reduce: 44 VGPR, zero spill.
__device__ __forceinline__ void conv1_item_body(
        int b, int strip, const float* __restrict__ x, const float* __restrict__ w,
        const float* __restrict__ bias, const bool* gp,
        float* __restrict__ stats1p, float* __restrict__ p1ext,
        float* red, int tid, int witem) {
    int pc = tid & 127;
    int rhalf = tid >> 7;
    int r0 = strip * 16 + rhalf * 8;
    const float* xb = x + (size_t)b * H1 * W1;
    float sums[8], sqs[8], pm[8];
#pragma unroll
    for (int c = 0; c < 8; c++) { sums[c] = 0.f; sqs[c] = 0.f; }
    bool act = pc < W2;
    if (act) {
        bool cl = pc > 0, cr = pc < W2 - 1;
        const float* rp0 = xb + (size_t)r0 * W1 + 2 * pc;
        float al, am0, am1, ar, bl, bm0, bm1, br;
        if (r0 > 0) {
            const float* rp = rp0 - W1;
            float2 m = *(const float2*)rp;
            al = cl ? rp[-1] : 0.f; am0 = m.x; am1 = m.y; ar = cr ? rp[2] : 0.f;
        } else { al = 0.f; am0 = 0.f; am1 = 0.f; ar = 0.f; }
        {
            float2 m = *(const float2*)rp0;
            bl = cl ? rp0[-1] : 0.f; bm0 = m.x; bm1 = m.y; br = cr ? rp0[2] : 0.f;
        }
#pragma unroll
        for (int rr = 0; rr < 8; rr++) {
            float nl = 0.f, nm0 = 0.f, nm1 = 0.f, nr = 0.f;
            int rn = r0 + rr + 1;
            if (rn < H1) {
                const float* rp = rp0 + (size_t)(rr + 1) * W1;
                float2 m = *(const float2*)rp;
                nl = cl ? rp[-1] : 0.f; nm0 = m.x; nm1 = m.y; nr = cr ? rp[2] : 0.f;
            }
            float4 e0 = make_float4(0.f, 0.f, 0.f, 0.f);
            float4 e1 = make_float4(0.f, 0.f, 0.f, 0.f);
#pragma unroll
            for (int c = 0; c < 8; c++) {
                const float* wc = w + c * 9;
                float y0 = bias[c], y1 = bias[c];
                y0 = fmaf(wc[0], al,  y0); y0 = fmaf(wc[1], am0, y0); y0 = fmaf(wc[2], am1, y0);
                y1 = fmaf(wc[0], am0, y1); y1 = fmaf(wc[1], am1, y1); y1 = fmaf(wc[2], ar,  y1);
                y0 = fmaf(wc[3], bl,  y0); y0 = fmaf(wc[4], bm0, y0); y0 = fmaf(wc[5], bm1, y0);
                y1 = fmaf(wc[3], bm0, y1); y1 = fmaf(wc[4], bm1, y1); y1 = fmaf(wc[5], br,  y1);
                y0 = fmaf(wc[6], nl,  y0); y0 = fmaf(wc[7], nm0, y0); y0 = fmaf(wc[8], nm1, y0);
                y1 = fmaf(wc[6], nm0, y1); y1 = fmaf(wc[7], nm1, y1); y1 = fmaf(wc[8], nr,  y1);
                sums[c] += y0 + y1;
                sqs[c] = fmaf(y0, y0, fmaf(y1, y1, sqs[c]));
                float m01 = gp[c] ? fmaxf(y0, y1) : fminf(y0, y1);
                if ((rr & 1) == 0) {
                    pm[c] = m01;
                } else {
                    float e = gp[c] ? fmaxf(pm[c], m01) : fminf(pm[c], m01);
                    if (c == 0) e0.x = e; else if (c == 1) e0.y = e;
                    else if (c == 2) e0.z = e; else if (c == 3) e0.w = e;
                    else if (c == 4) e1.x = e; else if (c == 5) e1.y = e;
                    else if (c == 6) e1.z = e; else e1.w = e;
                }
            }
            if (rr & 1) {
                int pr = (r0 + rr) >> 1;
                float* dst = p1ext + ((((size_t)b * H2 + pr) * W2 + pc) << 3);
                ((float4*)dst)[0] = e0;
                ((float4*)dst)[1] = e1;
            }
            al = bl; am0 = bm0; am1 = bm1; ar = br;
            bl = nl; bm0 = nm0; bm1 = nm1; br = nr;
        }
    }
    float vals[16];
#pragma unroll
    for (int c = 0; c < 8; c++) { vals[c] = sums[c]; vals[8 + c] = sqs[c]; }
    rows_reduce<16>(red, vals, tid);
    if (tid < 16) stats1p[((size_t)witem << 4) + tid] = red[tid * 256];
}

// conv2 item: one 32x32 tile. Needs h1t = 8*34*34 floats of LDS (also used as red).
__device__ __forceinline__ void conv2_item_body(
        int b, int Y0, int X0, const float* __restrict__ p1ext,
        const float* sc1, const float* sh1,
        const float* __restrict__ w2, const float* __restrict__ b2,
        const float* __restrict__ g2,
        float* __restrict__ stats2p, float* __restrict__ p2ext,
        float* smem, int tid, int witem) {
    float (*h1t)[34][34] = (float(*)[34][34])smem;
    int ty = tid >> 4, tx = tid & 15;
    const float* pb = p1ext + (((size_t)b * H2) * W2 << 3);
    for (int i = tid; i < 34 * 34; i += 256) {
        int p = i / 34, q = i % 34;
        int hy = Y0 - 1 + p, hx = X0 - 1 + q;
        if (hy >= 0 && hy < H2 && hx >= 0 && hx < W2) {
            const float* cp = pb + (((size_t)hy * W2 + hx) << 3);
            float4 u = ((const float4*)cp)[0];
            float4 v = ((const float4*)cp)[1];
            h1t[0][p][q] = fmaxf(fmaf(u.x, sc1[0], sh1[0]), 0.f);
            h1t[1][p][q] = fmaxf(fmaf(u.y, sc1[1], sh1[1]), 0.f);
            h1t[2][p][q] = fmaxf(fmaf(u.z, sc1[2], sh1[2]), 0.f);
            h1t[3][p][q] = fmaxf(fmaf(u.w, sc1[3], sh1[3]), 0.f);
            h1t[4][p][q] = fmaxf(fmaf(v.x, sc1[4], sh1[4]), 0.f);
            h1t[5][p][q] = fmaxf(fmaf(v.y, sc1[5], sh1[5]), 0.f);
            h1t[6][p][q] = fmaxf(fmaf(v.z, sc1[6], sh1[6]), 0.f);
            h1t[7][p][q] = fmaxf(fmaf(v.w, sc1[7], sh1[7]), 0.f);
        } else {
#pragma unroll
            for (int c = 0; c < 8; c++) h1t[c][p][q] = 0.f;
        }
    }
    __syncthreads();
    float acc[4][2][2];
#pragma unroll
    for (int co = 0; co < 4; co++)
#pragma unroll
        for (int dy = 0; dy < 2; dy++)
#pragma unroll
            for (int dx = 0; dx < 2; dx++) acc[co][dy][dx] = b2[co];
#pragma unroll
    for (int ci = 0; ci < 8; ci++) {
        float win[4][4];
#pragma unroll
        for (int r = 0; r < 4; r++) {
            const float2* rp = (const float2*)&h1t[ci][2 * ty + r][2 * tx];
            float2 u = rp[0], v = rp[1];
            win[r][0] = u.x; win[r][1] = u.y; win[r][2] = v.x; win[r][3] = v.y;
        }
#pragma unroll
        for (int co = 0; co < 4; co++)
#pragma unroll
            for (int ky = 0; ky < 3; ky++)
#pragma unroll
                for (int kx = 0; kx < 3; kx++) {
                    float wv = w2[co * 72 + ci * 9 + ky * 3 + kx];
#pragma unroll
                    for (int dy = 0; dy < 2; dy++)
#pragma unroll
                        for (int dx = 0; dx < 2; dx++)
                            acc[co][dy][dx] = fmaf(wv, win[dy + ky][dx + kx], acc[co][dy][dx]);
                }
    }
    int cy0 = Y0 + 2 * ty, cx0 = X0 + 2 * tx;
    bool vy0 = cy0 < H2, vy1 = cy0 + 1 < H2, vx0 = cx0 < W2, vx1 = cx0 + 1 < W2;
    float vals[8];
#pragma unroll
    for (int co = 0; co < 4; co++) {
        float s = 0.f, q = 0.f;
        if (vy0 && vx0) { float a = acc[co][0][0]; s += a; q = fmaf(a, a, q); }
        if (vy0 && vx1) { float a = acc[co][0][1]; s += a; q = fmaf(a, a, q); }
        if (vy1 && vx0) { float a = acc[co][1][0]; s += a; q = fmaf(a, a, q); }
        if (vy1 && vx1) { float a = acc[co][1][1]; s += a; q = fmaf(a, a, q); }
        vals[co] = s;
        vals[4 + co] = q;
    }
    {
        int hy = (Y0 >> 1) + ty, hx = (X0 >> 1) + tx;
        if (hy < HP && hx < WP) {
#pragma unroll
            for (int co = 0; co < 4; co++) {
                float mx = fmaxf(fmaxf(acc[co][0][0], acc[co][0][1]),
                                 fmaxf(acc[co][1][0], acc[co][1][1]));
                float mn = fminf(fminf(acc[co][0][0], acc[co][0][1]),
                                 fminf(acc[co][1][0], acc[co][1][1]));
                p2ext[(((size_t)b * 4 + co) * HP + hy) * WP + hx] = (g2[co] >= 0.f) ? mx : mn;
            }
        }
    }
    __syncthreads();
    rows_reduce<8>(smem, vals, tid);
    if (tid < 8) stats2p[((size_t)witem << 3) + tid] = smem[tid * 256];
}

// pool item: inline stats2 reduce + BN2+relu spatial sum. Needs 1040 floats of LDS.
__device__ __forceinline__ void pool_item_body(
        int b, int co, const float* __restrict__ p2ext,
        const float* __restrict__ g2, const float* __restrict__ be2,
        const float* __restrict__ stats2p, int nblk2,
        float* __restrict__ featbuf, float N2, float* red, int tid) {
    {
        const float4* sp = (const float4*)stats2p;
        int tot4 = nblk2 << 1;
        float4 a0 = make_float4(0.f, 0.f, 0.f, 0.f);
        float4 a1 = a0;
        int idx = tid;
        for (; idx + 256 < tot4; idx += 512) {
            float4 t0 = sp[idx];
            float4 t1 = sp[idx + 256];
            a0.x += t0.x; a0.y += t0.y; a0.z += t0.z; a0.w += t0.w;
            a1.x += t1.x; a1.y += t1.y; a1.z += t1.z; a1.w += t1.w;
        }
        for (; idx < tot4; idx += 256) {
            float4 t = sp[idx];
            a0.x += t.x; a0.y += t.y; a0.z += t.z; a0.w += t.w;
        }
        a0.x += a1.x; a0.y += a1.y; a0.z += a1.z; a0.w += a1.w;
        ((float4*)red)[tid] = a0;
    }
    __syncthreads();
    if (tid < 8) {
        int hi = tid >> 2, lo = tid & 3;
        float s = 0.f;
#pragma unroll
        for (int k = 0; k < 128; k++) s += red[((hi + (k << 1)) << 2) + lo];
        red[1024 + tid] = s;
    }
    __syncthreads();
    float su = red[1024 + co], sq = red[1024 + 4 + co];
    float mu = su / N2;
    float var = sq / N2 - mu * mu;
    float sc = g2[co] * rsqrtf(var + 1e-5f);
    float sh = be2[co] - mu * sc;
    const float4* P4 = (const float4*)(p2ext + ((size_t)b * 4 + co) * (HP * WP));
    float s = 0.f;
    for (int i = tid; i < (HP * WP) / 4; i += 256) {
        float4 t = P4[i];
        s += fmaxf(fmaf(t.x, sc, sh), 0.f) + fmaxf(fmaf(t.y, sc, sh), 0.f) +
             fmaxf(fmaf(t.z, sc, sh), 0.f) + fmaxf(fmaf(t.w, sc, sh), 0.f);
    }
    __syncthreads();
    red[tid] = s;
    __syncthreads();
    for (int st = 128; st > 0; st >>= 1) {
        if (tid < st) red[tid] += red[tid + st];
        __syncthreads();
    }
    if (tid == 0) featbuf[(size_t)b * 4 + co] = red[0];
}

// ---------------- batch-sum helper (block-wide, inactive lanes pass 0) ----------------
__device__ __forceinline__ float bsum(float v, float* lds) {
#pragma unroll
    for (int off = 32; off; off >>= 1) v += __shfl_xor(v, off, 64);
    __syncthreads();
    if ((threadIdx.x & 63) == 0) lds[threadIdx.x >> 6] = v;
    __syncthreads();
    float r = 0.f;
    int nw = (int)(blockDim.x + 63) >> 6;
#pragma clang loop unroll(disable)
    for (int i = 0; i < nw; i++) r += lds[i];
    return r;
}

// finalize body: guarded for blockDim >= B (inactive lanes contribute 0)
__device__ __forceinline__ void finalize_body(
        const float* __restrict__ featbuf, const float* __restrict__ theta,
        const float* __restrict__ rho, const float* __restrict__ ng,
        const float* __restrict__ nb, float* __restrict__ out, int B, float* lds) {
    int b = threadIdx.x;
    bool act = b < B;
    float f[4];
#pragma unroll
    for (int j = 0; j < 4; j++) f[j] = act ? featbuf[b * 4 + j] * (1.f / (HP * WP)) : 0.f;
    float n = 4.f * (float)B;
    float mean = bsum(f[0] + f[1] + f[2] + f[3], lds) / n;
    float d2 = 0.f;
    if (act) {
#pragma unroll
        for (int j = 0; j < 4; j++) { float d = f[j] - mean; d2 += d * d; }
    }
    float var1 = bsum(d2, lds) / (n - 1.f);
    float stdv = sqrtf(fmaxf(var1, 0.f)) + 1e-6f;
    const float PI = 3.14159265358979323846f;
    float cs[4], sn[4];
#pragma unroll
    for (int j = 0; j < 4; j++) {
        float sc = (f[j] - mean) / stdv * PI;
        cs[j] = cosf(0.5f * sc);
        sn[j] = sinf(0.5f * sc);
    }
    C2 st[16];
    {
        float amp[16];
        amp[1] = sn[3]; amp[0] = cs[3];
#pragma unroll
        for (int k = 0; k < 2; k++) { amp[k + 2] = amp[k] * sn[2]; amp[k] *= cs[2]; }
#pragma unroll
        for (int k = 0; k < 4; k++) { amp[k + 4] = amp[k] * sn[1]; amp[k] *= cs[1]; }
#pragma unroll
        for (int k = 0; k < 8; k++) { amp[k + 8] = amp[k] * sn[0]; amp[k] *= cs[0]; }
#pragma unroll
        for (int i = 0; i < 16; i++) st[i] = C2{amp[i], 0.f};
    }
#pragma clang loop unroll(disable)
    for (int l = 0; l < 2; l++) {
        const float* p = (l == 0) ? theta : rho;
#pragma clang loop unroll(disable)
        for (int i = 0; i < 4; i++) {
            M2 U = combined_u(p + i * 3);
            switch (i) {
            case 0: ap1s<8>(st, U.m[0][0], U.m[0][1], U.m[1][0], U.m[1][1]); break;
            case 1: ap1s<4>(st, U.m[0][0], U.m[0][1], U.m[1][0], U.m[1][1]); break;
            case 2: ap1s<2>(st, U.m[0][0], U.m[0][1], U.m[1][0], U.m[1][1]); break;
            default: ap1s<1>(st, U.m[0][0], U.m[0][1], U.m[1][0], U.m[1][1]); break;
            }
        }
        if (l == 0) { cnot_s<8, 4>(st); cnot_s<4, 2>(st); cnot_s<2, 1>(st); }
        else        { cnot_s<4, 8>(st); cnot_s<2, 4>(st); cnot_s<1, 2>(st); }
    }
    float e[4];
#pragma unroll
    for (int qb = 0; qb < 4; qb++) {
        int m = 8 >> qb;
        float p0 = 0.f, p1 = 0.f;
#pragma unroll
        for (int i = 0; i < 16; i++) {
            float pr = st[i].re * st[i].re + st[i].im * st[i].im;
            if (i & m) p1 += pr; else p0 += pr;
        }
        e[qb] = p0 - p1;
    }
#pragma clang loop unroll(disable)
    for (int j = 0; j < 4; j++) {
        float mu = bsum(act ? e[j] : 0.f, lds) / (float)B;
        float dv = e[j] - mu;
        float v = bsum(act ? dv * dv : 0.f, lds) / (float)B;
        if (act) out[b * 4 + j] = fmaf(dv, rsqrtf(v + 1e-5f) * ng[j], nb[j]);
    }
}

// ================= tier-A kernels (5 launches) =================

__global__ __launch_bounds__(256, 2) void conv1_pool_stats(
        const float* __restrict__ x, const float* __restrict__ w,
        const float* __restrict__ bias, const float* __restrict__ g1,
        float* __restrict__ stats1p, float* __restrict__ p1ext) {
    __shared__ float red[16 * 256];
    int strip = blockIdx.x;
    int b = blockIdx.y;
    int tid = threadIdx.x;
    bool gp[8];
#pragma unroll
    for (int c = 0; c < 8; c++) gp[c] = g1[c] >= 0.f;
    conv1_item_body(b, strip, x, w, bias, gp, stats1p, p1ext, red, tid, b * 14 + strip);
}

// 1-block kernel: reduce conv1 partials -> BN1 affine (sc1[8] | sh1[8]) in aff1.
// Replaces the per-conv2-block 114 KB prologue broadcast (235 MB of L2 traffic).
__global__ void affine1(const float* __restrict__ stats1p, int nblk1,
                        const float* __restrict__ g1, const float* __restrict__ be1,
                        float* __restrict__ aff1, float N1) {
    __shared__ float scr[1024 + 16];
    int tid = threadIdx.x;
    const float4* sp = (const float4*)stats1p;
    int tot4 = nblk1 << 2;
    float4 a0 = make_float4(0.f, 0.f, 0.f, 0.f);
    float4 a1 = a0, a2 = a0, a3 = a0;
    int idx = tid;
    for (; idx + 768 < tot4; idx += 1024) {
        float4 t0 = sp[idx];
        float4 t1 = sp[idx + 256];
        float4 t2 = sp[idx + 512];
        float4 t3 = sp[idx + 768];
        a0.x += t0.x; a0.y += t0.y; a0.z += t0.z; a0.w += t0.w;
        a1.x += t1.x; a1.y += t1.y; a1.z += t1.z; a1.w += t1.w;
        a2.x += t2.x; a2.y += t2.y; a2.z += t2.z; a2.w += t2.w;
        a3.x += t3.x; a3.y += t3.y; a3.z += t3.z; a3.w += t3.w;
    }
    for (; idx < tot4; idx += 256) {
        float4 t = sp[idx];
        a0.x += t.x; a0.y += t.y; a0.z += t.z; a0.w += t.w;
    }
    a0.x += a1.x + a2.x + a3.x;
    a0.y += a1.y + a2.y + a3.y;
    a0.z += a1.z + a2.z + a3.z;
    a0.w += a1.w + a2.w + a3.w;
    ((float4*)scr)[tid] = a0;                // scr[4*tid+j] holds class (tid&3)*4+j
    __syncthreads();
    if (tid < 16) {
        int hi = tid >> 2, lo = tid & 3;     // class tid = 4*hi + lo
        float s = 0.f;
#pragma unroll
        for (int k = 0; k < 64; k++) s += scr[((hi + (k << 2)) << 2) + lo];
        scr[1024 + tid] = s;
    }
    __syncthreads();
    if (tid < 8) {
        float su = scr[1024 + tid], sq = scr[1024 + 8 + tid];
        float mu = su / N1;
        float var = sq / N1 - mu * mu;
        float sc = g1[tid] * rsqrtf(var + 1e-5f);
        aff1[tid] = sc;
        aff1[8 + tid] = be1[tid] - mu * sc;
    }
}

__global__ __launch_bounds__(256, 4) void conv2_stats_slim(
        const float* __restrict__ p1ext, const float* __restrict__ aff1,
        const float* __restrict__ w2, const float* __restrict__ b2,
        const float* __restrict__ g2,
        float* __restrict__ stats2p, float* __restrict__ p2ext) {
    __shared__ __align__(16) float smem[8 * 34 * 34];
    __shared__ float sc1[8], sh1[8];
    int b = blockIdx.z;
    int tid = threadIdx.y * 16 + threadIdx.x;
    if (tid < 8) { sc1[tid] = aff1[tid]; sh1[tid] = aff1[8 + tid]; }
    __syncthreads();
    int blkid = (blockIdx.z * gridDim.y + blockIdx.y) * gridDim.x + blockIdx.x;
    conv2_item_body(b, blockIdx.y * 32, blockIdx.x * 32, p1ext, sc1, sh1,
                    w2, b2, g2, stats2p, p2ext, smem, tid, blkid);
}

__global__ void pool_bn_mean_p(const float* __restrict__ p2ext,
                               const float* __restrict__ g2, const float* __restrict__ be2,
                               const float* __restrict__ stats2p, int nblk2,
                               float* __restrict__ featbuf, float N2) {
    __shared__ float red[1024 + 16];
    pool_item_body(blockIdx.x >> 2, blockIdx.x & 3, p2ext, g2, be2, stats2p, nblk2,
                   featbuf, N2, red, threadIdx.x);
}

__global__ void finalize(const float* __restrict__ featbuf, const float* __restrict__ theta,
                         const float* __restrict__ rho, const float* __restrict__ ng,
                         const float* __restrict__ nb, float* __restrict__ out, int B) {
    __shared__ float lds[16];
    finalize_body(featbuf, theta, rho, ng, nb, out, B, lds);
}

// ================= tier B/C kernels (unchanged) =================

__global__ void conv1_stats(const float* __restrict__ x, const float* __restrict__ w,
                            const float* __restrict__ bias, float* __restrict__ stats) {
    __shared__ float red[16 * 256];
    int strip = blockIdx.x;
    int b = blockIdx.y;
    int tid = threadIdx.x;
    const float* xb = x + (size_t)b * H1 * W1;
    float sums[8], sqs[8];
#pragma unroll
    for (int c = 0; c < 8; c++) { sums[c] = 0.f; sqs[c] = 0.f; }
    int col = tid;
    if (col < W1) {
        bool cl = col > 0, cr = col < W1 - 1;
        int row0 = strip * 8;
        float a0, a1, a2, b0, b1, b2, c0, c1, c2;
        {
            int r = row0 - 1;
            if (r >= 0) {
                a0 = cl ? xb[r * W1 + col - 1] : 0.f;
                a1 = xb[r * W1 + col];
                a2 = cr ? xb[r * W1 + col + 1] : 0.f;
            } else { a0 = a1 = a2 = 0.f; }
            r = row0;
            b0 = cl ? xb[r * W1 + col - 1] : 0.f;
            b1 = xb[r * W1 + col];
            b2 = cr ? xb[r * W1 + col + 1] : 0.f;
        }
        for (int rr = 0; rr < 8; rr++) {
            int rn = row0 + rr + 1;
            if (rn < H1) {
                c0 = cl ? xb[rn * W1 + col - 1] : 0.f;
                c1 = xb[rn * W1 + col];
                c2 = cr ? xb[rn * W1 + col + 1] : 0.f;
            } else { c0 = c1 = c2 = 0.f; }
#pragma unroll
            for (int c = 0; c < 8; c++) {
                float acc = bias[c];
                acc = fmaf(w[c * 9 + 0], a0, acc);
                acc = fmaf(w[c * 9 + 1], a1, acc);
                acc = fmaf(w[c * 9 + 2], a2, acc);
                acc = fmaf(w[c * 9 + 3], b0, acc);
                acc = fmaf(w[c * 9 + 4], b1, acc);
                acc = fmaf(w[c * 9 + 5], b2, acc);
                acc = fmaf(w[c * 9 + 6], c0, acc);
                acc = fmaf(w[c * 9 + 7], c1, acc);
                acc = fmaf(w[c * 9 + 8], c2, acc);
                sums[c] += acc;
                sqs[c] = fmaf(acc, acc, sqs[c]);
            }
            a0 = b0; a1 = b1; a2 = b2;
            b0 = c0; b1 = c1; b2 = c2;
        }
    }
    float vals[16];
#pragma unroll
    for (int c = 0; c < 8; c++) { vals[c] = sums[c]; vals[8 + c] = sqs[c]; }
    rows_reduce<16>(red, vals, tid);
    int slot = (b * 28 + strip) & (NS - 1);
    if (tid < 16) atomicAdd(stats + slot * SLOT_STRIDE + tid, red[tid * 256]);
}

template <int PH, int PW>
__device__ __forceinline__ void build_h1_tile(const float* __restrict__ xb,
                                              float (*h1t)[PH][PW],
                                              const float* __restrict__ w1,
                                              const float* __restrict__ b1,
                                              const float* sc1, const float* sh1,
                                              int oy0, int ox0, int tid) {
    for (int i = tid; i < PH * PW; i += 256) {
        int p = i / PW, q = i % PW;
        int hy = oy0 + p, hx = ox0 + q;
        bool ok = (hy >= 0 && hy < H2 && hx >= 0 && hx < W2);
        float xp[5][5];
        if (hy >= 1 && hy <= H2 - 2 && hx >= 1 && hx <= W2 - 2) {
            const float* bp = xb + (2 * hy - 1) * W1 + (2 * hx - 1);
#pragma unroll
            for (int r = 0; r < 5; r++)
#pragma unroll
                for (int c = 0; c < 5; c++) xp[r][c] = bp[r * W1 + c];
        } else if (ok) {
#pragma unroll
            for (int r = 0; r < 5; r++)
#pragma unroll
                for (int c = 0; c < 5; c++) {
                    int gy = 2 * hy - 1 + r, gx = 2 * hx - 1 + c;
                    xp[r][c] = (gy >= 0 && gy < H1 && gx >= 0 && gx < W1) ? xb[gy * W1 + gx] : 0.f;
                }
        }
#pragma unroll
        for (int c = 0; c < 8; c++) {
            float mx = 0.f;
            if (ok) {
                mx = -INFINITY;
#pragma unroll
                for (int dy = 0; dy < 2; dy++)
#pragma unroll
                    for (int dx = 0; dx < 2; dx++) {
                        float acc = b1[c];
#pragma unroll
                        for (int ky = 0; ky < 3; ky++)
#pragma unroll
                            for (int kx = 0; kx < 3; kx++)
                                acc = fmaf(w1[c * 9 + ky * 3 + kx], xp[dy + ky][dx + kx], acc);
                        mx = fmaxf(mx, fmaxf(fmaf(acc, sc1[c], sh1[c]), 0.f));
                    }
            }
            h1t[c][p][q] = mx;
        }
    }
}

template <bool STORE>
__global__ __launch_bounds__(256, 4) void conv2_stats_fused(
        const float* __restrict__ x, const float* __restrict__ w1,
        const float* __restrict__ b1, const float* __restrict__ g1,
        const float* __restrict__ be1, const float* __restrict__ stats1,
        const float* __restrict__ w2, const float* __restrict__ b2,
        float* __restrict__ stats2,
        float* __restrict__ pmax, float* __restrict__ pmin, float N1) {
    __shared__ __align__(16) float h1t[8][34][34];
    __shared__ float sc1[8], sh1[8];
    int b = blockIdx.z;
    int Y0 = blockIdx.y * 32, X0 = blockIdx.x * 32;
    int ty = threadIdx.y, tx = threadIdx.x;
    int tid = ty * 16 + tx;
    if (tid < 8) {
        float su = slot_sum(stats1, tid), sq = slot_sum(stats1, 8 + tid);
        float mu = su / N1;
        float var = sq / N1 - mu * mu;
        float sc = g1[tid] * rsqrtf(var + 1e-5f);
        sc1[tid] = sc;
        sh1[tid] = be1[tid] - mu * sc;
    }
    __syncthreads();
    const float* xb = x + (size_t)b * H1 * W1;
    build_h1_tile<34, 34>(xb, h1t, w1, b1, sc1, sh1, Y0 - 1, X0 - 1, tid);
    __syncthreads();
    float acc[4][2][2];
#pragma unroll
    for (int co = 0; co < 4; co++)
#pragma unroll
        for (int dy = 0; dy < 2; dy++)
#pragma unroll
            for (int dx = 0; dx < 2; dx++) acc[co][dy][dx] = b2[co];
#pragma unroll
    for (int ci = 0; ci < 8; ci++) {
        float win[4][4];
#pragma unroll
        for (int r = 0; r < 4; r++) {
            const float2* rp = (const float2*)&h1t[ci][2 * ty + r][2 * tx];
            float2 u = rp[0], v = rp[1];
            win[r][0] = u.x; win[r][1] = u.y; win[r][2] = v.x; win[r][3] = v.y;
        }
#pragma unroll
        for (int co = 0; co < 4; co++)
#pragma unroll
            for (int ky = 0; ky < 3; ky++)
#pragma unroll
                for (int kx = 0; kx < 3; kx++) {
                    float wv = w2[co * 72 + ci * 9 + ky * 3 + kx];
#pragma unroll
                    for (int dy = 0; dy < 2; dy++)
#pragma unroll
                        for (int dx = 0; dx < 2; dx++)
                            acc[co][dy][dx] = fmaf(wv, win[dy + ky][dx + kx], acc[co][dy][dx]);
                }
    }
    int cy0 = Y0 + 2 * ty, cx0 = X0 + 2 * tx;
    bool vy0 = cy0 < H2, vy1 = cy0 + 1 < H2, vx0 = cx0 < W2, vx1 = cx0 + 1 < W2;
    float vals[8];
#pragma unroll
    for (int co = 0; co < 4; co++) {
        float s = 0.f, q = 0.f;
        if (vy0 && vx0) { float a = acc[co][0][0]; s += a; q = fmaf(a, a, q); }
        if (vy0 && vx1) { float a = acc[co][0][1]; s += a; q = fmaf(a, a, q); }
        if (vy1 && vx0) { float a = acc[co][1][0]; s += a; q = fmaf(a, a, q); }
        if (vy1 && vx1) { float a = acc[co][1][1]; s += a; q = fmaf(a, a, q); }
        vals[co] = s;
        vals[4 + co] = q;
    }
    if (STORE) {
        int hy = (Y0 >> 1) + ty, hx = (X0 >> 1) + tx;
        if (hy < HP && hx < WP) {
#pragma unroll
            for (int co = 0; co < 4; co++) {
                float mx = fmaxf(fmaxf(acc[co][0][0], acc[co][0][1]),
                                 fmaxf(acc[co][1][0], acc[co][1][1]));
                float mn = fminf(fminf(acc[co][0][0], acc[co][0][1]),
                                 fminf(acc[co][1][0], acc[co][1][1]));
                size_t idx = (((size_t)b * 4 + co) * HP + hy) * WP + hx;
                pmax[idx] = mx;
                pmin[idx] = mn;
            }
        }
    }
    __syncthreads();
    float* red = (float*)h1t;
    rows_reduce<8>(red, vals, tid);
    int slot = ((b * 16) + blockIdx.y * 4 + blockIdx.x) & (NS - 1);
    if (tid < 8) atomicAdd(stats2 + slot * SLOT_STRIDE + tid, red[tid * 256]);
}

__global__ void pool_bn_mean(const float* __restrict__ pmax, const float* __restrict__ pmin,
                             const float* __restrict__ g2, const float* __restrict__ be2,
                             const float* __restrict__ stats2,
                             float* __restrict__ featbuf, float N2) {
    __shared__ float red[256];
    int co = blockIdx.x & 3;
    int b = blockIdx.x >> 2;
    int tid = threadIdx.x;
    float su = slot_sum(stats2, co), sq = slot_sum(stats2, 4 + co);
    float mu = su / N2;
    float var = sq / N2 - mu * mu;
    float sc = g2[co] * rsqrtf(var + 1e-5f);
    float sh = be2[co] - mu * sc;
    const float* P = (sc >= 0.f ? pmax : pmin) + ((size_t)b * 4 + co) * (HP * WP);
    float s = 0.f;
    for (int i = tid; i < HP * WP; i += 256) s += fmaxf(fmaf(P[i], sc, sh), 0.f);
    red[tid] = s;
    __syncthreads();
    for (int st = 128; st > 0; st >>= 1) {
        if (tid < st) red[tid] += red[tid + st];
        __syncthreads();
    }
    if (tid == 0) featbuf[(size_t)b * 4 + co] = red[0];
}

__global__ void conv2_final_fused(const float* __restrict__ x, const float* __restrict__ w1,
                                  const float* __restrict__ b1, const float* __restrict__ g1,
                                  const float* __restrict__ be1,
                                  const float* __restrict__ stats1,
                                  const float* __restrict__ w2, const float* __restrict__ b2,
                                  const float* __restrict__ g2, const float* __restrict__ be2,
                                  const float* __restrict__ stats2,
                                  float* __restrict__ featbuf, float N1, float N2) {
    __shared__ __align__(16) float h1t[8][34][34];
    __shared__ float sc1[8], sh1[8];
    __shared__ float sc2[4], sh2[4];
    int b = blockIdx.z;
    int py0 = blockIdx.y * 16, px0 = blockIdx.x * 16;
    int ty = threadIdx.y, tx = threadIdx.x;
    int tid = ty * 16 + tx;
    if (tid < 8) {
        float su = slot_sum(stats1, tid), sq = slot_sum(stats1, 8 + tid);
        float mu = su / N1;
        float var = sq / N1 - mu * mu;
        float sc = g1[tid] * rsqrtf(var + 1e-5f);
        sc1[tid] = sc;
        sh1[tid] = be1[tid] - mu * sc;
    }
    if (tid >= 16 && tid < 20) {
        int j = tid - 16;
        float su = slot_sum(stats2, j), sq = slot_sum(stats2, 4 + j);
        float mu = su / N2;
        float var = sq / N2 - mu * mu;
        float sc = g2[j] * rsqrtf(var + 1e-5f);
        sc2[j] = sc;
        sh2[j] = be2[j] - mu * sc;
    }
    __syncthreads();
    const float* xb = x + (size_t)b * H1 * W1;
    build_h1_tile<34, 34>(xb, h1t, w1, b1, sc1, sh1, 2 * py0 - 1, 2 * px0 - 1, tid);
    __syncthreads();
    bool valid = (py0 + ty < HP) && (px0 + tx < WP);
    float acc[4][2][2];
#pragma unroll
    for (int co = 0; co < 4; co++)
#pragma unroll
        for (int dy = 0; dy < 2; dy++)
#pragma unroll
            for (int dx = 0; dx < 2; dx++) acc[co][dy][dx] = b2[co];
#pragma unroll
    for (int ci = 0; ci < 8; ci++) {
        float win[4][4];
#pragma unroll
        for (int r = 0; r < 4; r++) {
            const float2* rp = (const float2*)&h1t[ci][2 * ty + r][2 * tx];
            float2 u = rp[0], v = rp[1];
            win[r][0] = u.x; win[r][1] = u.y; win[r][2] = v.x; win[r][3] = v.y;
        }
#pragma unroll
        for (int co = 0; co < 4; co++)
#pragma unroll
            for (int ky = 0; ky < 3; ky++)
#pragma unroll
                for (int kx = 0; kx < 3; kx++) {
                    float wv = w2[co * 72 + ci * 9 + ky * 3 + kx];
#pragma unroll
                    for (int dy = 0; dy < 2; dy++)
#pragma unroll
                        for (int dx = 0; dx < 2; dx++)
                            acc[co][dy][dx] = fmaf(wv, win[dy + ky][dx + kx], acc[co][dy][dx]);
                }
    }
    float vals[4];
#pragma unroll
    for (int co = 0; co < 4; co++) {
        float mx = -INFINITY;
#pragma unroll
        for (int dy = 0; dy < 2; dy++)
#pragma unroll
            for (int dx = 0; dx < 2; dx++)
                mx = fmaxf(mx, fmaxf(fmaf(acc[co][dy][dx], sc2[co], sh2[co]), 0.f));
        vals[co] = valid ? mx : 0.f;
    }
    __syncthreads();
    float* red = (float*)h1t;
    rows_reduce<4>(red, vals, tid);
    if (tid < 4) atomicAdd(featbuf + (size_t)b * 4 + tid, red[tid * 256]);
}

// ================= host launcher =================
extern "C" void kernel_launch(void* const* d_in, const int* in_sizes, int n_in,
                              void* d_out, int out_size, void* d_ws, size_t ws_size,
                              hipStream_t stream) {
    const float* x     = (const float*)d_in[0];
    const float* w1    = (const float*)d_in[1];
    const float* b1    = (const float*)d_in[2];
    const float* g1    = (const float*)d_in[3];
    const float* be1   = (const float*)d_in[4];
    const float* w2    = (const float*)d_in[5];
    const float* b2    = (const float*)d_in[6];
    const float* g2    = (const float*)d_in[7];
    const float* be2   = (const float*)d_in[8];
    const float* theta = (const float*)d_in[9];
    const float* rho   = (const float*)d_in[10];
    const float* ng    = (const float*)d_in[11];
    const float* nb    = (const float*)d_in[12];
    float* out = (float*)d_out;

    int B = in_sizes[0] / (H1 * W1);

    float N1 = (float)B * H1 * W1;
    float N2 = (float)B * H2 * W2;

    int nblk1 = 14 * B;
    int nblk2 = 16 * B;

    size_t p2n = (size_t)B * 4 * HP * WP;
    size_t p1n = (size_t)B * 8 * H2 * W2;

    // tier A layout: stats1p | stats2p | aff1[16] | featbuf | p2ext | p1ext (no pre-zero)
    size_t offs1p = 0;
    size_t offs2p = offs1p + (size_t)nblk1 * 16;
    size_t offaff = offs2p + (size_t)nblk2 * 8;
    size_t offfb  = offaff + 16;
    size_t offp2  = offfb + (size_t)B * 4;
    size_t offp1  = offp2 + p2n;
    size_t needA  = (offp1 + p1n) * sizeof(float);

    size_t common = (size_t)(2 * NS * SLOT_STRIDE) + (size_t)B * 4;
    size_t needB = (common + 2 * p2n) * sizeof(float);

    bool tierA = ws_size >= needA;                    // constant per process -> graph-safe
    bool tierB = !tierA && ws_size >= needB;

    float* ws = (float*)d_ws;

    if (tierA) {
        float* stats1p = ws + offs1p;
        float* stats2p = ws + offs2p;
        float* aff1    = ws + offaff;
        float* featbuf = ws + offfb;
        float* p2ext   = ws + offp2;
        float* p1ext   = ws + offp1;
        conv1_pool_stats<<<dim3(14, B), 256, 0, stream>>>(x, w1, b1, g1, stats1p, p1ext);
        affine1<<<1, 256, 0, stream>>>(stats1p, nblk1, g1, be1, aff1, N1);
        conv2_stats_slim<<<dim3(4, 4, B), dim3(16, 16), 0, stream>>>(
            p1ext, aff1, w2, b2, g2, stats2p, p2ext);
        pool_bn_mean_p<<<B * 4, 256, 0, stream>>>(p2ext, g2, be2, stats2p, nblk2, featbuf, N2);
        finalize<<<1, 256, 0, stream>>>(featbuf, theta, rho, ng, nb, out, B);
    } else if (tierB) {
        float* stats1 = ws;
        float* stats2 = ws + NS * SLOT_STRIDE;
        float* featbuf = ws + 2 * NS * SLOT_STRIDE;
        float* bufs = featbuf + (size_t)B * 4;
        float* pmax = bufs;
        float* pmin = bufs + p2n;
        int nz = (int)common;
        zero_ws<<<(nz + 255) / 256, 256, 0, stream>>>(ws, nz);
        conv1_stats<<<dim3(28, B), 256, 0, stream>>>(x, w1, b1, stats1);
        conv2_stats_fused<true><<<dim3(4, 4, B), dim3(16, 16), 0, stream>>>(
            x, w1, b1, g1, be1, stats1, w2, b2, stats2, pmax, pmin, N1);
        pool_bn_mean<<<B * 4, 256, 0, stream>>>(pmax, pmin, g2, be2, stats2, featbuf, N2);
        finalize<<<1, 256, 0, stream>>>(featbuf, theta, rho, ng, nb, out, B);
    } else {
        float* stats1 = ws;
        float* stats2 = ws + NS * SLOT_STRIDE;
        float* featbuf = ws + 2 * NS * SLOT_STRIDE;
        int nz = (int)common;
        zero_ws<<<(nz + 255) / 256, 256, 0, stream>>>(ws, nz);
        conv1_stats<<<dim3(28, B), 256, 0, stream>>>(x, w1, b1, stats1);
        conv2_stats_fused<false><<<dim3(4, 4, B), dim3(16, 16), 0, stream>>>(
            x, w1, b1, g1, be1, stats1, w2, b2, stats2, nullptr, nullptr, N1);
        conv2_final_fused<<<dim3(4, 4, B), dim3(16, 16), 0, stream>>>(
            x, w1, b1, g1, be1, stats1, w2, b2, g2, be2, stats2, featbuf, N1, N2);
        finalize<<<1, 256, 0, stream>>>(featbuf, theta, rho, ng, nb, out, B);
    }
}

// Round 12
// 161.690 us; speedup vs baseline: 1.6035x; 1.0570x over previous
//
#include <hip/hip_runtime.h>
#include <math.h>

#define H1 224
#define W1 224
#define H2 112
#define W2 112
#define HP 56
#define WP 56

#define NS 32
#define SLOT_STRIDE 64

// ---------------- complex helpers (quantum circuit) ----------------
struct C2 { float re, im; };
__device__ __forceinline__ C2 cmul(C2 a, C2 b) {
    return C2{fmaf(a.re, b.re, -a.im * b.im), fmaf(a.re, b.im, a.im * b.re)};
}
__device__ __forceinline__ C2 cadd(C2 a, C2 b) { return C2{a.re + b.re, a.im + b.im}; }

template <int S>
__device__ __forceinline__ void ap1s(C2* st, C2 u00, C2 u01, C2 u10, C2 u11) {
#pragma unroll
    for (int i = 0; i < 16; i++) {
        if (i & S) continue;
        C2 a0 = st[i], a1 = st[i + S];
        st[i]     = cadd(cmul(u00, a0), cmul(u01, a1));
        st[i + S] = cadd(cmul(u10, a0), cmul(u11, a1));
    }
}
template <int SC, int STT>
__device__ __forceinline__ void cnot_s(C2* st) {
#pragma unroll
    for (int i = 0; i < 16; i++)
        if ((i & SC) && !(i & STT)) { C2 t = st[i]; st[i] = st[i + STT]; st[i + STT] = t; }
}
struct M2 { C2 m[2][2]; };
__device__ __forceinline__ M2 mmul(const M2& A, const M2& B) {
    M2 R;
#pragma unroll
    for (int i = 0; i < 2; i++)
#pragma unroll
        for (int j = 0; j < 2; j++)
            R.m[i][j] = cadd(cmul(A.m[i][0], B.m[0][j]), cmul(A.m[i][1], B.m[1][j]));
    return R;
}
// combined U = Rx(p2) * Rz(p1) * Ry(p0)
__device__ __forceinline__ M2 combined_u(const float* __restrict__ p) {
    float c0 = cosf(0.5f * p[0]), s0 = sinf(0.5f * p[0]);
    float c1 = cosf(0.5f * p[1]), s1 = sinf(0.5f * p[1]);
    float c2 = cosf(0.5f * p[2]), s2 = sinf(0.5f * p[2]);
    M2 Ry = {{{{c0, 0.f}, {-s0, 0.f}}, {{s0, 0.f}, {c0, 0.f}}}};
    M2 Rz = {{{{c1, -s1}, {0.f, 0.f}}, {{0.f, 0.f}, {c1, s1}}}};
    M2 Rx = {{{{c2, 0.f}, {0.f, -s2}}, {{0.f, -s2}, {c2, 0.f}}}};
    return mmul(Rx, mmul(Rz, Ry));
}

// ---------------- multi-row LDS tree reduction (256 threads, Q rows) ----------------
template <int Q>
__device__ __forceinline__ void rows_reduce(float* red, const float* vals, int tid) {
#pragma unroll
    for (int q = 0; q < Q; q++) red[q * 256 + tid] = vals[q];
    __syncthreads();
#pragma unroll
    for (int s = 128; s > 0; s >>= 1) {
        for (int idx = tid; idx < Q * s; idx += 256) {
            int row = idx / s, i = idx - row * s;
            red[row * 256 + i] += red[row * 256 + i + s];
        }
        __syncthreads();
    }
}

__global__ void zero_ws(float* ws, int n) {
    int i = blockIdx.x * blockDim.x + threadIdx.x;
    if (i < n) ws[i] = 0.f;
}

__device__ __forceinline__ float slot_sum(const float* stats, int c) {
    float s = 0.f;
#pragma unroll
    for (int sl = 0; sl < NS; sl++) s += stats[sl * SLOT_STRIDE + c];
    return s;
}

// ================= shared phase bodies =================

// conv1 item: one 16-row strip of one image. Needs red = 16*256 floats of LDS.
// v3 (R12): ALL 10 row-loads batched upfront into rowv[10][4] -> 30 independent loads
// in ONE latency window (the rolling-window version serialized 8 windows).
// Live ~100 VGPR; (256,2) budget ~128 (R8-R10 empirical: budget = 256/min_waves) -> no spill.
__device__ __forceinline__ void conv1_item_body(
        int b, int strip, const float* __restrict__ x, const float* __restrict__ w,
        const float* __restrict__ bias, const bool* gp,
        float* __restrict__ stats1p, float* __restrict__ p1ext,
        float* red, int tid, int witem) {
    int pc = tid & 127;
    int rhalf = tid >> 7;
    int r0 = strip * 16 + rhalf * 8;
    const float* xb = x + (size_t)b * H1 * W1;
    float sums[8], sqs[8], pm[8];
#pragma unroll
    for (int c = 0; c < 8; c++) { sums[c] = 0.f; sqs[c] = 0.f; }
    bool act = pc < W2;
    if (act) {
        bool cl = pc > 0, cr = pc < W2 - 1;
        const float* rp0 = xb + (size_t)r0 * W1 + 2 * pc;
        // batched load: rows r0-1 .. r0+8 -> rowv[0..9] = {l, m0, m1, r}
        float rowv[10][4];
#pragma unroll
        for (int rr = 0; rr < 10; rr++) {
            int gr = r0 + rr - 1;
            if (gr >= 0 && gr < H1) {
                const float* rp = rp0 + (ptrdiff_t)(rr - 1) * W1;
                float2 m = *(const float2*)rp;
                rowv[rr][0] = cl ? rp[-1] : 0.f;
                rowv[rr][1] = m.x;
                rowv[rr][2] = m.y;
                rowv[rr][3] = cr ? rp[2] : 0.f;
            } else {
                rowv[rr][0] = 0.f; rowv[rr][1] = 0.f;
                rowv[rr][2] = 0.f; rowv[rr][3] = 0.f;
            }
        }
#pragma unroll
        for (int rr = 0; rr < 8; rr++) {
            const float* A = rowv[rr];
            const float* Bv = rowv[rr + 1];
            const float* Nv = rowv[rr + 2];
            float4 e0 = make_float4(0.f, 0.f, 0.f, 0.f);
            float4 e1 = make_float4(0.f, 0.f, 0.f, 0.f);
#pragma unroll
            for (int c = 0; c < 8; c++) {
                const float* wc = w + c * 9;
                float y0 = bias[c], y1 = bias[c];
                y0 = fmaf(wc[0], A[0],  y0); y0 = fmaf(wc[1], A[1],  y0); y0 = fmaf(wc[2], A[2],  y0);
                y1 = fmaf(wc[0], A[1],  y1); y1 = fmaf(wc[1], A[2],  y1); y1 = fmaf(wc[2], A[3],  y1);
                y0 = fmaf(wc[3], Bv[0], y0); y0 = fmaf(wc[4], Bv[1], y0); y0 = fmaf(wc[5], Bv[2], y0);
                y1 = fmaf(wc[3], Bv[1], y1); y1 = fmaf(wc[4], Bv[2], y1); y1 = fmaf(wc[5], Bv[3], y1);
                y0 = fmaf(wc[6], Nv[0], y0); y0 = fmaf(wc[7], Nv[1], y0); y0 = fmaf(wc[8], Nv[2], y0);
                y1 = fmaf(wc[6], Nv[1], y1); y1 = fmaf(wc[7], Nv[2], y1); y1 = fmaf(wc[8], Nv[3], y1);
                sums[c] += y0 + y1;
                sqs[c] = fmaf(y0, y0, fmaf(y1, y1, sqs[c]));
                float m01 = gp[c] ? fmaxf(y0, y1) : fminf(y0, y1);
                if ((rr & 1) == 0) {
                    pm[c] = m01;
                } else {
                    float e = gp[c] ? fmaxf(pm[c], m01) : fminf(pm[c], m01);
                    if (c == 0) e0.x = e; else if (c == 1) e0.y = e;
                    else if (c == 2) e0.z = e; else if (c == 3) e0.w = e;
                    else if (c == 4) e1.x = e; else if (c == 5) e1.y = e;
                    else if (c == 6) e1.z = e; else e1.w = e;
                }
            }
            if (rr & 1) {
                int pr = (r0 + rr) >> 1;
                float* dst = p1ext + ((((size_t)b * H2 + pr) * W2 + pc) << 3);
                ((float4*)dst)[0] = e0;
                ((float4*)dst)[1] = e1;
            }
        }
    }
    float vals[16];
#pragma unroll
    for (int c = 0; c < 8; c++) { vals[c] = sums[c]; vals[8 + c] = sqs[c]; }
    rows_reduce<16>(red, vals, tid);
    if (tid < 16) stats1p[((size_t)witem << 4) + tid] = red[tid * 256];
}

// conv2 item: one 32x32 tile. Needs h1t = 8*34*34 floats of LDS (also used as red).
__device__ __forceinline__ void conv2_item_body(
        int b, int Y0, int X0, const float* __restrict__ p1ext,
        const float* sc1, const float* sh1,
        const float* __restrict__ w2, const float* __restrict__ b2,
        const float* __restrict__ g2,
        float* __restrict__ stats2p, float* __restrict__ p2ext,
        float* smem, int tid, int witem) {
    float (*h1t)[34][34] = (float(*)[34][34])smem;
    int ty = tid >> 4, tx = tid & 15;
    const float* pb = p1ext + (((size_t)b * H2) * W2 << 3);
    for (int i = tid; i < 34 * 34; i += 256) {
        int p = i / 34, q = i % 34;
        int hy = Y0 - 1 + p, hx = X0 - 1 + q;
        if (hy >= 0 && hy < H2 && hx >= 0 && hx < W2) {
            const float* cp = pb + (((size_t)hy * W2 + hx) << 3);
            float4 u = ((const float4*)cp)[0];
            float4 v = ((const float4*)cp)[1];
            h1t[0][p][q] = fmaxf(fmaf(u.x, sc1[0], sh1[0]), 0.f);
            h1t[1][p][q] = fmaxf(fmaf(u.y, sc1[1], sh1[1]), 0.f);
            h1t[2][p][q] = fmaxf(fmaf(u.z, sc1[2], sh1[2]), 0.f);
            h1t[3][p][q] = fmaxf(fmaf(u.w, sc1[3], sh1[3]), 0.f);
            h1t[4][p][q] = fmaxf(fmaf(v.x, sc1[4], sh1[4]), 0.f);
            h1t[5][p][q] = fmaxf(fmaf(v.y, sc1[5], sh1[5]), 0.f);
            h1t[6][p][q] = fmaxf(fmaf(v.z, sc1[6], sh1[6]), 0.f);
            h1t[7][p][q] = fmaxf(fmaf(v.w, sc1[7], sh1[7]), 0.f);
        } else {
#pragma unroll
            for (int c = 0; c < 8; c++) h1t[c][p][q] = 0.f;
        }
    }
    __syncthreads();
    float acc[4][2][2];
#pragma unroll
    for (int co = 0; co < 4; co++)
#pragma unroll
        for (int dy = 0; dy < 2; dy++)
#pragma unroll
            for (int dx = 0; dx < 2; dx++) acc[co][dy][dx] = b2[co];
#pragma unroll
    for (int ci = 0; ci < 8; ci++) {
        float win[4][4];
#pragma unroll
        for (int r = 0; r < 4; r++) {
            const float2* rp = (const float2*)&h1t[ci][2 * ty + r][2 * tx];
            float2 u = rp[0], v = rp[1];
            win[r][0] = u.x; win[r][1] = u.y; win[r][2] = v.x; win[r][3] = v.y;
        }
#pragma unroll
        for (int co = 0; co < 4; co++)
#pragma unroll
            for (int ky = 0; ky < 3; ky++)
#pragma unroll
                for (int kx = 0; kx < 3; kx++) {
                    float wv = w2[co * 72 + ci * 9 + ky * 3 + kx];
#pragma unroll
                    for (int dy = 0; dy < 2; dy++)
#pragma unroll
                        for (int dx = 0; dx < 2; dx++)
                            acc[co][dy][dx] = fmaf(wv, win[dy + ky][dx + kx], acc[co][dy][dx]);
                }
    }
    int cy0 = Y0 + 2 * ty, cx0 = X0 + 2 * tx;
    bool vy0 = cy0 < H2, vy1 = cy0 + 1 < H2, vx0 = cx0 < W2, vx1 = cx0 + 1 < W2;
    float vals[8];
#pragma unroll
    for (int co = 0; co < 4; co++) {
        float s = 0.f, q = 0.f;
        if (vy0 && vx0) { float a = acc[co][0][0]; s += a; q = fmaf(a, a, q); }
        if (vy0 && vx1) { float a = acc[co][0][1]; s += a; q = fmaf(a, a, q); }
        if (vy1 && vx0) { float a = acc[co][1][0]; s += a; q = fmaf(a, a, q); }
        if (vy1 && vx1) { float a = acc[co][1][1]; s += a; q = fmaf(a, a, q); }
        vals[co] = s;
        vals[4 + co] = q;
    }
    {
        int hy = (Y0 >> 1) + ty, hx = (X0 >> 1) + tx;
        if (hy < HP && hx < WP) {
#pragma unroll
            for (int co = 0; co < 4; co++) {
                float mx = fmaxf(fmaxf(acc[co][0][0], acc[co][0][1]),
                                 fmaxf(acc[co][1][0], acc[co][1][1]));
                float mn = fminf(fminf(acc[co][0][0], acc[co][0][1]),
                                 fminf(acc[co][1][0], acc[co][1][1]));
                p2ext[(((size_t)b * 4 + co) * HP + hy) * WP + hx] = (g2[co] >= 0.f) ? mx : mn;
            }
        }
    }
    __syncthreads();
    rows_reduce<8>(smem, vals, tid);
    if (tid < 8) stats2p[((size_t)witem << 3) + tid] = smem[tid * 256];
}

// pool item: inline stats2 reduce + BN2+relu spatial sum. Needs 1040 floats of LDS.
__device__ __forceinline__ void pool_item_body(
        int b, int co, const float* __restrict__ p2ext,
        const float* __restrict__ g2, const float* __restrict__ be2,
        const float* __restrict__ stats2p, int nblk2,
        float* __restrict__ featbuf, float N2, float* red, int tid) {
    {
        const float4* sp = (const float4*)stats2p;
        int tot4 = nblk2 << 1;
        float4 a0 = make_float4(0.f, 0.f, 0.f, 0.f);
        float4 a1 = a0;
        int idx = tid;
        for (; idx + 256 < tot4; idx += 512) {
            float4 t0 = sp[idx];
            float4 t1 = sp[idx + 256];
            a0.x += t0.x; a0.y += t0.y; a0.z += t0.z; a0.w += t0.w;
            a1.x += t1.x; a1.y += t1.y; a1.z += t1.z; a1.w += t1.w;
        }
        for (; idx < tot4; idx += 256) {
            float4 t = sp[idx];
            a0.x += t.x; a0.y += t.y; a0.z += t.z; a0.w += t.w;
        }
        a0.x += a1.x; a0.y += a1.y; a0.z += a1.z; a0.w += a1.w;
        ((float4*)red)[tid] = a0;
    }
    __syncthreads();
    if (tid < 8) {
        int hi = tid >> 2, lo = tid & 3;
        float s = 0.f;
#pragma unroll
        for (int k = 0; k < 128; k++) s += red[((hi + (k << 1)) << 2) + lo];
        red[1024 + tid] = s;
    }
    __syncthreads();
    float su = red[1024 + co], sq = red[1024 + 4 + co];
    float mu = su / N2;
    float var = sq / N2 - mu * mu;
    float sc = g2[co] * rsqrtf(var + 1e-5f);
    float sh = be2[co] - mu * sc;
    const float4* P4 = (const float4*)(p2ext + ((size_t)b * 4 + co) * (HP * WP));
    float s = 0.f;
    for (int i = tid; i < (HP * WP) / 4; i += 256) {
        float4 t = P4[i];
        s += fmaxf(fmaf(t.x, sc, sh), 0.f) + fmaxf(fmaf(t.y, sc, sh), 0.f) +
             fmaxf(fmaf(t.z, sc, sh), 0.f) + fmaxf(fmaf(t.w, sc, sh), 0.f);
    }
    __syncthreads();
    red[tid] = s;
    __syncthreads();
    for (int st = 128; st > 0; st >>= 1) {
        if (tid < st) red[tid] += red[tid + st];
        __syncthreads();
    }
    if (tid == 0) featbuf[(size_t)b * 4 + co] = red[0];
}

// ---------------- batch-sum helper (block-wide, inactive lanes pass 0) ----------------
__device__ __forceinline__ float bsum(float v, float* lds) {
#pragma unroll
    for (int off = 32; off; off >>= 1) v += __shfl_xor(v, off, 64);
    __syncthreads();
    if ((threadIdx.x & 63) == 0) lds[threadIdx.x >> 6] = v;
    __syncthreads();
    float r = 0.f;
    int nw = (int)(blockDim.x + 63) >> 6;
#pragma clang loop unroll(disable)
    for (int i = 0; i < nw; i++) r += lds[i];
    return r;
}

// finalize body: guarded for blockDim >= B (inactive lanes contribute 0)
__device__ __forceinline__ void finalize_body(
        const float* __restrict__ featbuf, const float* __restrict__ theta,
        const float* __restrict__ rho, const float* __restrict__ ng,
        const float* __restrict__ nb, float* __restrict__ out, int B, float* lds) {
    int b = threadIdx.x;
    bool act = b < B;
    float f[4];
#pragma unroll
    for (int j = 0; j < 4; j++) f[j] = act ? featbuf[b * 4 + j] * (1.f / (HP * WP)) : 0.f;
    float n = 4.f * (float)B;
    float mean = bsum(f[0] + f[1] + f[2] + f[3], lds) / n;
    float d2 = 0.f;
    if (act) {
#pragma unroll
        for (int j = 0; j < 4; j++) { float d = f[j] - mean; d2 += d * d; }
    }
    float var1 = bsum(d2, lds) / (n - 1.f);
    float stdv = sqrtf(fmaxf(var1, 0.f)) + 1e-6f;
    const float PI = 3.14159265358979323846f;
    float cs[4], sn[4];
#pragma unroll
    for (int j = 0; j < 4; j++) {
        float sc = (f[j] - mean) / stdv * PI;
        cs[j] = cosf(0.5f * sc);
        sn[j] = sinf(0.5f * sc);
    }
    C2 st[16];
    {
        float amp[16];
        amp[1] = sn[3]; amp[0] = cs[3];
#pragma unroll
        for (int k = 0; k < 2; k++) { amp[k + 2] = amp[k] * sn[2]; amp[k] *= cs[2]; }
#pragma unroll
        for (int k = 0; k < 4; k++) { amp[k + 4] = amp[k] * sn[1]; amp[k] *= cs[1]; }
#pragma unroll
        for (int k = 0; k < 8; k++) { amp[k + 8] = amp[k] * sn[0]; amp[k] *= cs[0]; }
#pragma unroll
        for (int i = 0; i < 16; i++) st[i] = C2{amp[i], 0.f};
    }
#pragma clang loop unroll(disable)
    for (int l = 0; l < 2; l++) {
        const float* p = (l == 0) ? theta : rho;
#pragma clang loop unroll(disable)
        for (int i = 0; i < 4; i++) {
            M2 U = combined_u(p + i * 3);
            switch (i) {
            case 0: ap1s<8>(st, U.m[0][0], U.m[0][1], U.m[1][0], U.m[1][1]); break;
            case 1: ap1s<4>(st, U.m[0][0], U.m[0][1], U.m[1][0], U.m[1][1]); break;
            case 2: ap1s<2>(st, U.m[0][0], U.m[0][1], U.m[1][0], U.m[1][1]); break;
            default: ap1s<1>(st, U.m[0][0], U.m[0][1], U.m[1][0], U.m[1][1]); break;
            }
        }
        if (l == 0) { cnot_s<8, 4>(st); cnot_s<4, 2>(st); cnot_s<2, 1>(st); }
        else        { cnot_s<4, 8>(st); cnot_s<2, 4>(st); cnot_s<1, 2>(st); }
    }
    float e[4];
#pragma unroll
    for (int qb = 0; qb < 4; qb++) {
        int m = 8 >> qb;
        float p0 = 0.f, p1 = 0.f;
#pragma unroll
        for (int i = 0; i < 16; i++) {
            float pr = st[i].re * st[i].re + st[i].im * st[i].im;
            if (i & m) p1 += pr; else p0 += pr;
        }
        e[qb] = p0 - p1;
    }
#pragma clang loop unroll(disable)
    for (int j = 0; j < 4; j++) {
        float mu = bsum(act ? e[j] : 0.f, lds) / (float)B;
        float dv = e[j] - mu;
        float v = bsum(act ? dv * dv : 0.f, lds) / (float)B;
        if (act) out[b * 4 + j] = fmaf(dv, rsqrtf(v + 1e-5f) * ng[j], nb[j]);
    }
}

// ================= tier-A kernels (5 launches) =================

__global__ __launch_bounds__(256, 2) void conv1_pool_stats(
        const float* __restrict__ x, const float* __restrict__ w,
        const float* __restrict__ bias, const float* __restrict__ g1,
        float* __restrict__ stats1p, float* __restrict__ p1ext) {
    __shared__ float red[16 * 256];
    int strip = blockIdx.x;
    int b = blockIdx.y;
    int tid = threadIdx.x;
    bool gp[8];
#pragma unroll
    for (int c = 0; c < 8; c++) gp[c] = g1[c] >= 0.f;
    conv1_item_body(b, strip, x, w, bias, gp, stats1p, p1ext, red, tid, b * 14 + strip);
}

// 1-block kernel: reduce conv1 partials -> BN1 affine (sc1[8] | sh1[8]) in aff1.
__global__ void affine1(const float* __restrict__ stats1p, int nblk1,
                        const float* __restrict__ g1, const float* __restrict__ be1,
                        float* __restrict__ aff1, float N1) {
    __shared__ float scr[1024 + 16];
    int tid = threadIdx.x;
    const float4* sp = (const float4*)stats1p;
    int tot4 = nblk1 << 2;
    float4 a0 = make_float4(0.f, 0.f, 0.f, 0.f);
    float4 a1 = a0, a2 = a0, a3 = a0;
    int idx = tid;
    for (; idx + 768 < tot4; idx += 1024) {
        float4 t0 = sp[idx];
        float4 t1 = sp[idx + 256];
        float4 t2 = sp[idx + 512];
        float4 t3 = sp[idx + 768];
        a0.x += t0.x; a0.y += t0.y; a0.z += t0.z; a0.w += t0.w;
        a1.x += t1.x; a1.y += t1.y; a1.z += t1.z; a1.w += t1.w;
        a2.x += t2.x; a2.y += t2.y; a2.z += t2.z; a2.w += t2.w;
        a3.x += t3.x; a3.y += t3.y; a3.z += t3.z; a3.w += t3.w;
    }
    for (; idx < tot4; idx += 256) {
        float4 t = sp[idx];
        a0.x += t.x; a0.y += t.y; a0.z += t.z; a0.w += t.w;
    }
    a0.x += a1.x + a2.x + a3.x;
    a0.y += a1.y + a2.y + a3.y;
    a0.z += a1.z + a2.z + a3.z;
    a0.w += a1.w + a2.w + a3.w;
    ((float4*)scr)[tid] = a0;                // scr[4*tid+j] holds class (tid&3)*4+j
    __syncthreads();
    if (tid < 16) {
        int hi = tid >> 2, lo = tid & 3;     // class tid = 4*hi + lo
        float s = 0.f;
#pragma unroll
        for (int k = 0; k < 64; k++) s += scr[((hi + (k << 2)) << 2) + lo];
        scr[1024 + tid] = s;
    }
    __syncthreads();
    if (tid < 8) {
        float su = scr[1024 + tid], sq = scr[1024 + 8 + tid];
        float mu = su / N1;
        float var = sq / N1 - mu * mu;
        float sc = g1[tid] * rsqrtf(var + 1e-5f);
        aff1[tid] = sc;
        aff1[8 + tid] = be1[tid] - mu * sc;
    }
}

__global__ __launch_bounds__(256, 4) void conv2_stats_slim(
        const float* __restrict__ p1ext, const float* __restrict__ aff1,
        const float* __restrict__ w2, const float* __restrict__ b2,
        const float* __restrict__ g2,
        float* __restrict__ stats2p, float* __restrict__ p2ext) {
    __shared__ __align__(16) float smem[8 * 34 * 34];
    __shared__ float sc1[8], sh1[8];
    int b = blockIdx.z;
    int tid = threadIdx.y * 16 + threadIdx.x;
    if (tid < 8) { sc1[tid] = aff1[tid]; sh1[tid] = aff1[8 + tid]; }
    __syncthreads();
    int blkid = (blockIdx.z * gridDim.y + blockIdx.y) * gridDim.x + blockIdx.x;
    conv2_item_body(b, blockIdx.y * 32, blockIdx.x * 32, p1ext, sc1, sh1,
                    w2, b2, g2, stats2p, p2ext, smem, tid, blkid);
}

__global__ void pool_bn_mean_p(const float* __restrict__ p2ext,
                               const float* __restrict__ g2, const float* __restrict__ be2,
                               const float* __restrict__ stats2p, int nblk2,
                               float* __restrict__ featbuf, float N2) {
    __shared__ float red[1024 + 16];
    pool_item_body(blockIdx.x >> 2, blockIdx.x & 3, p2ext, g2, be2, stats2p, nblk2,
                   featbuf, N2, red, threadIdx.x);
}

__global__ void finalize(const float* __restrict__ featbuf, const float* __restrict__ theta,
                         const float* __restrict__ rho, const float* __restrict__ ng,
                         const float* __restrict__ nb, float* __restrict__ out, int B) {
    __shared__ float lds[16];
    finalize_body(featbuf, theta, rho, ng, nb, out, B, lds);
}

// ================= tier B/C kernels (unchanged) =================

__global__ void conv1_stats(const float* __restrict__ x, const float* __restrict__ w,
                            const float* __restrict__ bias, float* __restrict__ stats) {
    __shared__ float red[16 * 256];
    int strip = blockIdx.x;
    int b = blockIdx.y;
    int tid = threadIdx.x;
    const float* xb = x + (size_t)b * H1 * W1;
    float sums[8], sqs[8];
#pragma unroll
    for (int c = 0; c < 8; c++) { sums[c] = 0.f; sqs[c] = 0.f; }
    int col = tid;
    if (col < W1) {
        bool cl = col > 0, cr = col < W1 - 1;
        int row0 = strip * 8;
        float a0, a1, a2, b0, b1, b2, c0, c1, c2;
        {
            int r = row0 - 1;
            if (r >= 0) {
                a0 = cl ? xb[r * W1 + col - 1] : 0.f;
                a1 = xb[r * W1 + col];
                a2 = cr ? xb[r * W1 + col + 1] : 0.f;
            } else { a0 = a1 = a2 = 0.f; }
            r = row0;
            b0 = cl ? xb[r * W1 + col - 1] : 0.f;
            b1 = xb[r * W1 + col];
            b2 = cr ? xb[r * W1 + col + 1] : 0.f;
        }
        for (int rr = 0; rr < 8; rr++) {
            int rn = row0 + rr + 1;
            if (rn < H1) {
                c0 = cl ? xb[rn * W1 + col - 1] : 0.f;
                c1 = xb[rn * W1 + col];
                c2 = cr ? xb[rn * W1 + col + 1] : 0.f;
            } else { c0 = c1 = c2 = 0.f; }
#pragma unroll
            for (int c = 0; c < 8; c++) {
                float acc = bias[c];
                acc = fmaf(w[c * 9 + 0], a0, acc);
                acc = fmaf(w[c * 9 + 1], a1, acc);
                acc = fmaf(w[c * 9 + 2], a2, acc);
                acc = fmaf(w[c * 9 + 3], b0, acc);
                acc = fmaf(w[c * 9 + 4], b1, acc);
                acc = fmaf(w[c * 9 + 5], b2, acc);
                acc = fmaf(w[c * 9 + 6], c0, acc);
                acc = fmaf(w[c * 9 + 7], c1, acc);
                acc = fmaf(w[c * 9 + 8], c2, acc);
                sums[c] += acc;
                sqs[c] = fmaf(acc, acc, sqs[c]);
            }
            a0 = b0; a1 = b1; a2 = b2;
            b0 = c0; b1 = c1; b2 = c2;
        }
    }
    float vals[16];
#pragma unroll
    for (int c = 0; c < 8; c++) { vals[c] = sums[c]; vals[8 + c] = sqs[c]; }
    rows_reduce<16>(red, vals, tid);
    int slot = (b * 28 + strip) & (NS - 1);
    if (tid < 16) atomicAdd(stats + slot * SLOT_STRIDE + tid, red[tid * 256]);
}

template <int PH, int PW>
__device__ __forceinline__ void build_h1_tile(const float* __restrict__ xb,
                                              float (*h1t)[PH][PW],
                                              const float* __restrict__ w1,
                                              const float* __restrict__ b1,
                                              const float* sc1, const float* sh1,
                                              int oy0, int ox0, int tid) {
    for (int i = tid; i < PH * PW; i += 256) {
        int p = i / PW, q = i % PW;
        int hy = oy0 + p, hx = ox0 + q;
        bool ok = (hy >= 0 && hy < H2 && hx >= 0 && hx < W2);
        float xp[5][5];
        if (hy >= 1 && hy <= H2 - 2 && hx >= 1 && hx <= W2 - 2) {
            const float* bp = xb + (2 * hy - 1) * W1 + (2 * hx - 1);
#pragma unroll
            for (int r = 0; r < 5; r++)
#pragma unroll
                for (int c = 0; c < 5; c++) xp[r][c] = bp[r * W1 + c];
        } else if (ok) {
#pragma unroll
            for (int r = 0; r < 5; r++)
#pragma unroll
                for (int c = 0; c < 5; c++) {
                    int gy = 2 * hy - 1 + r, gx = 2 * hx - 1 + c;
                    xp[r][c] = (gy >= 0 && gy < H1 && gx >= 0 && gx < W1) ? xb[gy * W1 + gx] : 0.f;
                }
        }
#pragma unroll
        for (int c = 0; c < 8; c++) {
            float mx = 0.f;
            if (ok) {
                mx = -INFINITY;
#pragma unroll
                for (int dy = 0; dy < 2; dy++)
#pragma unroll
                    for (int dx = 0; dx < 2; dx++) {
                        float acc = b1[c];
#pragma unroll
                        for (int ky = 0; ky < 3; ky++)
#pragma unroll
                            for (int kx = 0; kx < 3; kx++)
                                acc = fmaf(w1[c * 9 + ky * 3 + kx], xp[dy + ky][dx + kx], acc);
                        mx = fmaxf(mx, fmaxf(fmaf(acc, sc1[c], sh1[c]), 0.f));
                    }
            }
            h1t[c][p][q] = mx;
        }
    }
}

template <bool STORE>
__global__ __launch_bounds__(256, 4) void conv2_stats_fused(
        const float* __restrict__ x, const float* __restrict__ w1,
        const float* __restrict__ b1, const float* __restrict__ g1,
        const float* __restrict__ be1, const float* __restrict__ stats1,
        const float* __restrict__ w2, const float* __restrict__ b2,
        float* __restrict__ stats2,
        float* __restrict__ pmax, float* __restrict__ pmin, float N1) {
    __shared__ __align__(16) float h1t[8][34][34];
    __shared__ float sc1[8], sh1[8];
    int b = blockIdx.z;
    int Y0 = blockIdx.y * 32, X0 = blockIdx.x * 32;
    int ty = threadIdx.y, tx = threadIdx.x;
    int tid = ty * 16 + tx;
    if (tid < 8) {
        float su = slot_sum(stats1, tid), sq = slot_sum(stats1, 8 + tid);
        float mu = su / N1;
        float var = sq / N1 - mu * mu;
        float sc = g1[tid] * rsqrtf(var + 1e-5f);
        sc1[tid] = sc;
        sh1[tid] = be1[tid] - mu * sc;
    }
    __syncthreads();
    const float* xb = x + (size_t)b * H1 * W1;
    build_h1_tile<34, 34>(xb, h1t, w1, b1, sc1, sh1, Y0 - 1, X0 - 1, tid);
    __syncthreads();
    float acc[4][2][2];
#pragma unroll
    for (int co = 0; co < 4; co++)
#pragma unroll
        for (int dy = 0; dy < 2; dy++)
#pragma unroll
            for (int dx = 0; dx < 2; dx++) acc[co][dy][dx] = b2[co];
#pragma unroll
    for (int ci = 0; ci < 8; ci++) {
        float win[4][4];
#pragma unroll
        for (int r = 0; r < 4; r++) {
            const float2* rp = (const float2*)&h1t[ci][2 * ty + r][2 * tx];
            float2 u = rp[0], v = rp[1];
            win[r][0] = u.x; win[r][1] = u.y; win[r][2] = v.x; win[r][3] = v.y;
        }
#pragma unroll
        for (int co = 0; co < 4; co++)
#pragma unroll
            for (int ky = 0; ky < 3; ky++)
#pragma unroll
                for (int kx = 0; kx < 3; kx++) {
                    float wv = w2[co * 72 + ci * 9 + ky * 3 + kx];
#pragma unroll
                    for (int dy = 0; dy < 2; dy++)
#pragma unroll
                        for (int dx = 0; dx < 2; dx++)
                            acc[co][dy][dx] = fmaf(wv, win[dy + ky][dx + kx], acc[co][dy][dx]);
                }
    }
    int cy0 = Y0 + 2 * ty, cx0 = X0 + 2 * tx;
    bool vy0 = cy0 < H2, vy1 = cy0 + 1 < H2, vx0 = cx0 < W2, vx1 = cx0 + 1 < W2;
    float vals[8];
#pragma unroll
    for (int co = 0; co < 4; co++) {
        float s = 0.f, q = 0.f;
        if (vy0 && vx0) { float a = acc[co][0][0]; s += a; q = fmaf(a, a, q); }
        if (vy0 && vx1) { float a = acc[co][0][1]; s += a; q = fmaf(a, a, q); }
        if (vy1 && vx0) { float a = acc[co][1][0]; s += a; q = fmaf(a, a, q); }
        if (vy1 && vx1) { float a = acc[co][1][1]; s += a; q = fmaf(a, a, q); }
        vals[co] = s;
        vals[4 + co] = q;
    }
    if (STORE) {
        int hy = (Y0 >> 1) + ty, hx = (X0 >> 1) + tx;
        if (hy < HP && hx < WP) {
#pragma unroll
            for (int co = 0; co < 4; co++) {
                float mx = fmaxf(fmaxf(acc[co][0][0], acc[co][0][1]),
                                 fmaxf(acc[co][1][0], acc[co][1][1]));
                float mn = fminf(fminf(acc[co][0][0], acc[co][0][1]),
                                 fminf(acc[co][1][0], acc[co][1][1]));
                size_t idx = (((size_t)b * 4 + co) * HP + hy) * WP + hx;
                pmax[idx] = mx;
                pmin[idx] = mn;
            }
        }
    }
    __syncthreads();
    float* red = (float*)h1t;
    rows_reduce<8>(red, vals, tid);
    int slot = ((b * 16) + blockIdx.y * 4 + blockIdx.x) & (NS - 1);
    if (tid < 8) atomicAdd(stats2 + slot * SLOT_STRIDE + tid, red[tid * 256]);
}

__global__ void pool_bn_mean(const float* __restrict__ pmax, const float* __restrict__ pmin,
                             const float* __restrict__ g2, const float* __restrict__ be2,
                             const float* __restrict__ stats2,
                             float* __restrict__ featbuf, float N2) {
    __shared__ float red[256];
    int co = blockIdx.x & 3;
    int b = blockIdx.x >> 2;
    int tid = threadIdx.x;
    float su = slot_sum(stats2, co), sq = slot_sum(stats2, 4 + co);
    float mu = su / N2;
    float var = sq / N2 - mu * mu;
    float sc = g2[co] * rsqrtf(var + 1e-5f);
    float sh = be2[co] - mu * sc;
    const float* P = (sc >= 0.f ? pmax : pmin) + ((size_t)b * 4 + co) * (HP * WP);
    float s = 0.f;
    for (int i = tid; i < HP * WP; i += 256) s += fmaxf(fmaf(P[i], sc, sh), 0.f);
    red[tid] = s;
    __syncthreads();
    for (int st = 128; st > 0; st >>= 1) {
        if (tid < st) red[tid] += red[tid + st];
        __syncthreads();
    }
    if (tid == 0) featbuf[(size_t)b * 4 + co] = red[0];
}

__global__ void conv2_final_fused(const float* __restrict__ x, const float* __restrict__ w1,
                                  const float* __restrict__ b1, const float* __restrict__ g1,
                                  const float* __restrict__ be1,
                                  const float* __restrict__ stats1,
                                  const float* __restrict__ w2, const float* __restrict__ b2,
                                  const float* __restrict__ g2, const float* __restrict__ be2,
                                  const float* __restrict__ stats2,
                                  float* __restrict__ featbuf, float N1, float N2) {
    __shared__ __align__(16) float h1t[8][34][34];
    __shared__ float sc1[8], sh1[8];
    __shared__ float sc2[4], sh2[4];
    int b = blockIdx.z;
    int py0 = blockIdx.y * 16, px0 = blockIdx.x * 16;
    int ty = threadIdx.y, tx = threadIdx.x;
    int tid = ty * 16 + tx;
    if (tid < 8) {
        float su = slot_sum(stats1, tid), sq = slot_sum(stats1, 8 + tid);
        float mu = su / N1;
        float var = sq / N1 - mu * mu;
        float sc = g1[tid] * rsqrtf(var + 1e-5f);
        sc1[tid] = sc;
        sh1[tid] = be1[tid] - mu * sc;
    }
    if (tid >= 16 && tid < 20) {
        int j = tid - 16;
        float su = slot_sum(stats2, j), sq = slot_sum(stats2, 4 + j);
        float mu = su / N2;
        float var = sq / N2 - mu * mu;
        float sc = g2[j] * rsqrtf(var + 1e-5f);
        sc2[j] = sc;
        sh2[j] = be2[j] - mu * sc;
    }
    __syncthreads();
    const float* xb = x + (size_t)b * H1 * W1;
    build_h1_tile<34, 34>(xb, h1t, w1, b1, sc1, sh1, 2 * py0 - 1, 2 * px0 - 1, tid);
    __syncthreads();
    bool valid = (py0 + ty < HP) && (px0 + tx < WP);
    float acc[4][2][2];
#pragma unroll
    for (int co = 0; co < 4; co++)
#pragma unroll
        for (int dy = 0; dy < 2; dy++)
#pragma unroll
            for (int dx = 0; dx < 2; dx++) acc[co][dy][dx] = b2[co];
#pragma unroll
    for (int ci = 0; ci < 8; ci++) {
        float win[4][4];
#pragma unroll
        for (int r = 0; r < 4; r++) {
            const float2* rp = (const float2*)&h1t[ci][2 * ty + r][2 * tx];
            float2 u = rp[0], v = rp[1];
            win[r][0] = u.x; win[r][1] = u.y; win[r][2] = v.x; win[r][3] = v.y;
        }
#pragma unroll
        for (int co = 0; co < 4; co++)
#pragma unroll
            for (int ky = 0; ky < 3; ky++)
#pragma unroll
                for (int kx = 0; kx < 3; kx++) {
                    float wv = w2[co * 72 + ci * 9 + ky * 3 + kx];
#pragma unroll
                    for (int dy = 0; dy < 2; dy++)
#pragma unroll
                        for (int dx = 0; dx < 2; dx++)
                            acc[co][dy][dx] = fmaf(wv, win[dy + ky][dx + kx], acc[co][dy][dx]);
                }
    }
    float vals[4];
#pragma unroll
    for (int co = 0; co < 4; co++) {
        float mx = -INFINITY;
#pragma unroll
        for (int dy = 0; dy < 2; dy++)
#pragma unroll
            for (int dx = 0; dx < 2; dx++)
                mx = fmaxf(mx, fmaxf(fmaf(acc[co][dy][dx], sc2[co], sh2[co]), 0.f));
        vals[co] = valid ? mx : 0.f;
    }
    __syncthreads();
    float* red = (float*)h1t;
    rows_reduce<4>(red, vals, tid);
    if (tid < 4) atomicAdd(featbuf + (size_t)b * 4 + tid, red[tid * 256]);
}

// ================= host launcher =================
extern "C" void kernel_launch(void* const* d_in, const int* in_sizes, int n_in,
                              void* d_out, int out_size, void* d_ws, size_t ws_size,
                              hipStream_t stream) {
    const float* x     = (const float*)d_in[0];
    const float* w1    = (const float*)d_in[1];
    const float* b1    = (const float*)d_in[2];
    const float* g1    = (const float*)d_in[3];
    const float* be1   = (const float*)d_in[4];
    const float* w2    = (const float*)d_in[5];
    const float* b2    = (const float*)d_in[6];
    const float* g2    = (const float*)d_in[7];
    const float* be2   = (const float*)d_in[8];
    const float* theta = (const float*)d_in[9];
    const float* rho   = (const float*)d_in[10];
    const float* ng    = (const float*)d_in[11];
    const float* nb    = (const float*)d_in[12];
    float* out = (float*)d_out;

    int B = in_sizes[0] / (H1 * W1);

    float N1 = (float)B * H1 * W1;
    float N2 = (float)B * H2 * W2;

    int nblk1 = 14 * B;
    int nblk2 = 16 * B;

    size_t p2n = (size_t)B * 4 * HP * WP;
    size_t p1n = (size_t)B * 8 * H2 * W2;

    // tier A layout: stats1p | stats2p | aff1[16] | featbuf | p2ext | p1ext (no pre-zero)
    size_t offs1p = 0;
    size_t offs2p = offs1p + (size_t)nblk1 * 16;
    size_t offaff = offs2p + (size_t)nblk2 * 8;
    size_t offfb  = offaff + 16;
    size_t offp2  = offfb + (size_t)B * 4;
    size_t offp1  = offp2 + p2n;
    size_t needA  = (offp1 + p1n) * sizeof(float);

    size_t common = (size_t)(2 * NS * SLOT_STRIDE) + (size_t)B * 4;
    size_t needB = (common + 2 * p2n) * sizeof(float);

    bool tierA = ws_size >= needA;                    // constant per process -> graph-safe
    bool tierB = !tierA && ws_size >= needB;

    float* ws = (float*)d_ws;

    if (tierA) {
        float* stats1p = ws + offs1p;
        float* stats2p = ws + offs2p;
        float* aff1    = ws + offaff;
        float* featbuf = ws + offfb;
        float* p2ext   = ws + offp2;
        float* p1ext   = ws + offp1;
        conv1_pool_stats<<<dim3(14, B), 256, 0, stream>>>(x, w1, b1, g1, stats1p, p1ext);
        affine1<<<1, 256, 0, stream>>>(stats1p, nblk1, g1, be1, aff1, N1);
        conv2_stats_slim<<<dim3(4, 4, B), dim3(16, 16), 0, stream>>>(
            p1ext, aff1, w2, b2, g2, stats2p, p2ext);
        pool_bn_mean_p<<<B * 4, 256, 0, stream>>>(p2ext, g2, be2, stats2p, nblk2, featbuf, N2);
        finalize<<<1, 256, 0, stream>>>(featbuf, theta, rho, ng, nb, out, B);
    } else if (tierB) {
        float* stats1 = ws;
        float* stats2 = ws + NS * SLOT_STRIDE;
        float* featbuf = ws + 2 * NS * SLOT_STRIDE;
        float* bufs = featbuf + (size_t)B * 4;
        float* pmax = bufs;
        float* pmin = bufs + p2n;
        int nz = (int)common;
        zero_ws<<<(nz + 255) / 256, 256, 0, stream>>>(ws, nz);
        conv1_stats<<<dim3(28, B), 256, 0, stream>>>(x, w1, b1, stats1);
        conv2_stats_fused<true><<<dim3(4, 4, B), dim3(16, 16), 0, stream>>>(
            x, w1, b1, g1, be1, stats1, w2, b2, stats2, pmax, pmin, N1);
        pool_bn_mean<<<B * 4, 256, 0, stream>>>(pmax, pmin, g2, be2, stats2, featbuf, N2);
        finalize<<<1, 256, 0, stream>>>(featbuf, theta, rho, ng, nb, out, B);
    } else {
        float* stats1 = ws;
        float* stats2 = ws + NS * SLOT_STRIDE;
        float* featbuf = ws + 2 * NS * SLOT_STRIDE;
        int nz = (int)common;
        zero_ws<<<(nz + 255) / 256, 256, 0, stream>>>(ws, nz);
        conv1_stats<<<dim3(28, B), 256, 0, stream>>>(x, w1, b1, stats1);
        conv2_stats_fused<false><<<dim3(4, 4, B), dim3(16, 16), 0, stream>>>(
            x, w1, b1, g1, be1, stats1, w2, b2, stats2, nullptr, nullptr, N1);
        conv2_final_fused<<<dim3(4, 4, B), dim3(16, 16), 0, stream>>>(
            x, w1, b1, g1, be1, stats1, w2, b2, g2, be2, stats2, featbuf, N1, N2);
        finalize<<<1, 256, 0, stream>>>(featbuf, theta, rho, ng, nb, out, B);
    }
}